// Round 2
// baseline (1695.708 us; speedup 1.0000x reference)
//
#include <hip/hip_runtime.h>
#include <hip/hip_fp16.h>

#define NN 20000
#define NE 100000

__device__ __forceinline__ float wred(float v) {
#pragma unroll
  for (int k = 1; k < 64; k <<= 1) v += __shfl_xor(v, k);
  return v;
}

__global__ void zerok(float* __restrict__ p, int n) {
  int i = blockIdx.x * 256 + threadIdx.x;
  if (i < n) p[i] = 0.f;
}

// ---- per-column sum / sumsq over [R, C] fp32 ----
template <int C>
__global__ void colstats(const float* __restrict__ x, float* __restrict__ stat, int total) {
  __shared__ float ls[2 * C];
  for (int i = threadIdx.x; i < 2 * C; i += blockDim.x) ls[i] = 0.f;
  __syncthreads();
  for (int idx = blockIdx.x * blockDim.x + threadIdx.x; idx < total; idx += gridDim.x * blockDim.x) {
    float v = x[idx];
    int c = idx % C;
    atomicAdd(&ls[c], v);
    atomicAdd(&ls[C + c], v * v);
  }
  __syncthreads();
  for (int i = threadIdx.x; i < 2 * C; i += blockDim.x) atomicAdd(&stat[i], ls[i]);
}

__global__ void finalize_bn(const float* __restrict__ stat, const float* __restrict__ g,
                            const float* __restrict__ b, float* __restrict__ s_out,
                            float* __restrict__ c_out, int C, float invR) {
  int c = blockIdx.x * blockDim.x + threadIdx.x;
  if (c >= C) return;
  float mean = stat[c] * invR;
  float var = fmaxf(stat[C + c] * invR - mean * mean, 0.f);
  float sc = g[c] * rsqrtf(var + 1e-5f);
  s_out[c] = sc;
  c_out[c] = b[c] - mean * sc;
}

__global__ void deg_kernel(const int* __restrict__ dst, float* __restrict__ deg, int E) {
  int e = blockIdx.x * blockDim.x + threadIdx.x;
  if (e < E) atomicAdd(&deg[dst[e]], 1.f);
}

__global__ void invden_kernel(const float* __restrict__ deg, float* __restrict__ inv, int N) {
  int n = blockIdx.x * blockDim.x + threadIdx.x;
  if (n < N) inv[n] = 1.f / fmaxf(deg[n], 1.f);
}

// ---- Wc[10,128] = edge_W @ en_W1 ; bc[128] = edge_b @ en_W1 + en_b1 ----
__global__ void fold_w1(const float* __restrict__ edge_W, const float* __restrict__ edge_b,
                        const float* __restrict__ en_W1, const float* __restrict__ en_b1,
                        float* __restrict__ Wc, float* __restrict__ bc) {
  int t = threadIdx.x;
  for (int idx = t; idx < 1280; idx += 256) {
    int bq = idx >> 7, j = idx & 127;
    float a = 0.f;
    for (int q = 0; q < 128; ++q) a += edge_W[bq * 128 + q] * en_W1[q * 128 + j];
    Wc[idx] = a;
  }
  if (t < 128) {
    float a = en_b1[t];
    for (int q = 0; q < 128; ++q) a += edge_b[q] * en_W1[q * 128 + t];
    bc[t] = a;
  }
}

// ---- Sx[10][10] + xsum[10] over xb = x*es+ec.  sxs: [0..100)=Sx, [100..110)=xsum ----
__global__ __launch_bounds__(64) void sx_kernel(const float* __restrict__ x,
                                                const float* __restrict__ es,
                                                const float* __restrict__ ec,
                                                float* __restrict__ sxs, int E) {
  float s[10][10], xs[10], esl[10], ecl[10];
#pragma unroll
  for (int a = 0; a < 10; ++a) {
    xs[a] = 0.f; esl[a] = es[a]; ecl[a] = ec[a];
#pragma unroll
    for (int b = 0; b < 10; ++b) s[a][b] = 0.f;
  }
  for (int e = blockIdx.x * 64 + threadIdx.x; e < E; e += gridDim.x * 64) {
    float xb[10];
#pragma unroll
    for (int q = 0; q < 10; ++q) xb[q] = x[(size_t)e * 10 + q] * esl[q] + ecl[q];
#pragma unroll
    for (int a = 0; a < 10; ++a) {
      xs[a] += xb[a];
#pragma unroll
      for (int b = 0; b < 10; ++b) s[a][b] += xb[a] * xb[b];
    }
  }
#pragma unroll
  for (int a = 0; a < 10; ++a) {
    float r = wred(xs[a]);
    if (threadIdx.x == 0) atomicAdd(&sxs[100 + a], r);
#pragma unroll
    for (int b = 0; b < 10; ++b) {
      float r2 = wred(s[a][b]);
      if (threadIdx.x == 0) atomicAdd(&sxs[a * 10 + b], r2);
    }
  }
}

// ---- BN1 scale/shift from Sx quadratic form (r1 = xb@Wc + bc, col j) ----
__global__ void bn1_from_sx(const float* __restrict__ sxs, const float* __restrict__ Wc,
                            const float* __restrict__ bc, const float* __restrict__ g,
                            const float* __restrict__ b, float* __restrict__ s1,
                            float* __restrict__ c1) {
  int j = threadIdx.x;  // 128
  float w[10];
#pragma unroll
  for (int q = 0; q < 10; ++q) w[q] = Wc[q * 128 + j];
  float d = 0.f;
#pragma unroll
  for (int q = 0; q < 10; ++q) d += sxs[100 + q] * w[q];
  float qq = 0.f;
#pragma unroll
  for (int a = 0; a < 10; ++a) {
    float p = 0.f;
#pragma unroll
    for (int bq = 0; bq < 10; ++bq) p += sxs[a * 10 + bq] * w[bq];
    qq += w[a] * p;
  }
  float invE = 1.f / (float)NE;
  float bias = bc[j];
  float mean = d * invE + bias;
  float m2 = (qq + 2.f * bias * d) * invE + bias * bias;
  float var = fmaxf(m2 - mean * mean, 0.f);
  float sc = g[j] * rsqrtf(var + 1e-5f);
  s1[j] = sc;
  c1[j] = b[j] - mean * sc;
}

// ---- t[e,j] = leaky(bn1(xb@Wc + bc))  -> fp16 [NE,128] ----
__global__ __launch_bounds__(256) void t_kernel(const float* __restrict__ x,
                                                const float* __restrict__ es,
                                                const float* __restrict__ ec,
                                                const float* __restrict__ Wc,
                                                const float* __restrict__ bcb,
                                                const float* __restrict__ s1,
                                                const float* __restrict__ c1,
                                                __half* __restrict__ T, int E) {
  __shared__ float Wcl[1280], bcl[128], s1l[128], c1l[128], esl[10], ecl[10];
  for (int i = threadIdx.x; i < 1280; i += 256) Wcl[i] = Wc[i];
  if (threadIdx.x < 128) {
    bcl[threadIdx.x] = bcb[threadIdx.x];
    s1l[threadIdx.x] = s1[threadIdx.x];
    c1l[threadIdx.x] = c1[threadIdx.x];
  }
  if (threadIdx.x < 10) { esl[threadIdx.x] = es[threadIdx.x]; ecl[threadIdx.x] = ec[threadIdx.x]; }
  __syncthreads();
  int gid = blockIdx.x * 256 + threadIdx.x;
  if (gid >= E * 128) return;
  int r = gid >> 7, j = gid & 127;
  float acc = bcl[j];
#pragma unroll
  for (int q = 0; q < 10; ++q) acc += (x[(size_t)r * 10 + q] * esl[q] + ecl[q]) * Wcl[q * 128 + j];
  float tv = acc * s1l[j] + c1l[j];
  tv = tv > 0.f ? tv : 0.8f * tv;
  T[gid] = __float2half(tv);
}

// ---- S[128][128] = sum_e t t^T ; tsum[128] = sum_e t ----
__global__ __launch_bounds__(256) void tsq_kernel(const __half* __restrict__ T,
                                                  float* __restrict__ S,
                                                  float* __restrict__ tsum, int E) {
  __shared__ float tt[16][128];
  int t = threadIdx.x;
  int ta = t >> 4, tb = t & 15;
  float acc[8][8];
#pragma unroll
  for (int a = 0; a < 8; ++a)
#pragma unroll
    for (int b = 0; b < 8; ++b) acc[a][b] = 0.f;
  float tsl = 0.f;
  int per = (E + gridDim.x - 1) / gridDim.x;
  int e0 = blockIdx.x * per;
  int e1 = min(E, e0 + per);
  for (int ec = e0; ec < e1; ec += 16) {
    __syncthreads();
    int rr = t >> 4, g8 = (t & 15) * 8;
    int e = ec + rr;
    uint4 u = make_uint4(0, 0, 0, 0);
    if (e < e1) u = *(const uint4*)&T[(size_t)e * 128 + g8];
    const __half* hp = (const __half*)&u;
#pragma unroll
    for (int q = 0; q < 8; ++q) tt[rr][g8 + q] = __half2float(hp[q]);
    __syncthreads();
    if (t < 128) {
#pragma unroll
      for (int r2 = 0; r2 < 16; ++r2) tsl += tt[r2][t];
    }
#pragma unroll
    for (int ee = 0; ee < 16; ++ee) {
      float va[8], vb[8];
#pragma unroll
      for (int q = 0; q < 8; ++q) { va[q] = tt[ee][ta * 8 + q]; vb[q] = tt[ee][tb * 8 + q]; }
#pragma unroll
      for (int a = 0; a < 8; ++a)
#pragma unroll
        for (int b = 0; b < 8; ++b) acc[a][b] += va[a] * vb[b];
    }
  }
#pragma unroll
  for (int a = 0; a < 8; ++a)
#pragma unroll
    for (int b = 0; b < 8; ++b) atomicAdd(&S[(ta * 8 + a) * 128 + tb * 8 + b], acc[a][b]);
  if (t < 128) atomicAdd(&tsum[t], tsl);
}

// ---- BN2 scale/shift from S quadratic form (raw col io: w = W2[:,io], bias b2[io]) ----
__global__ void bn2_from_s(const float* __restrict__ S, const float* __restrict__ tsum,
                           const float* __restrict__ W2, const float* __restrict__ b2,
                           const float* __restrict__ g, const float* __restrict__ b,
                           float* __restrict__ s2, float* __restrict__ c2) {
  int io = blockIdx.x * 256 + threadIdx.x;
  if (io >= 1024) return;
  float d = 0.f, qq = 0.f;
  for (int a = 0; a < 128; ++a) {
    float wa = W2[(size_t)a * 1024 + io];
    d += tsum[a] * wa;
    float p = 0.f;
    for (int bq = 0; bq < 128; ++bq) p += S[a * 128 + bq] * W2[(size_t)bq * 1024 + io];
    qq += wa * p;
  }
  float invE = 1.f / (float)NE;
  float bias = b2[io];
  float mean = d * invE + bias;
  float m2 = (qq + 2.f * bias * d) * invE + bias * bias;
  float var = fmaxf(m2 - mean * mean, 0.f);
  float sc = g[io] * rsqrtf(var + 1e-5f);
  s2[io] = sc;
  c2[io] = b[io] - mean * sc;
}

// ---- node embedding: out[r,j] = sum_k (x*s+c) W + bias ----
template <int K, int COUT>
__global__ __launch_bounds__(256) void embed_gemm(const float* __restrict__ x,
                                                  const float* __restrict__ s,
                                                  const float* __restrict__ c,
                                                  const float* __restrict__ W,
                                                  const float* __restrict__ bias,
                                                  float* __restrict__ out, int R) {
  __shared__ float Wl[K * COUT];
  __shared__ float sl[K], cl[K];
  for (int i = threadIdx.x; i < K * COUT; i += 256) Wl[i] = W[i];
  for (int i = threadIdx.x; i < K; i += 256) { sl[i] = s[i]; cl[i] = c[i]; }
  __syncthreads();
  int gid = blockIdx.x * 256 + threadIdx.x;
  if (gid >= R * COUT) return;
  int r = gid / COUT, j = gid % COUT;
  float acc = bias[j];
#pragma unroll
  for (int k = 0; k < K; ++k) acc += (x[(size_t)r * K + k] * sl[k] + cl[k]) * Wl[k * COUT + j];
  out[gid] = acc;
}

// ---- big GEMM: We[e,io] = (T[e,:]@W2[:,io] + b2[io])*s2[io] + c2[io]  -> fp16 ----
__global__ __launch_bounds__(256) void gemm2_kernel(const __half* __restrict__ T,
                                                    const float* __restrict__ W2,
                                                    const float* __restrict__ b2,
                                                    const float* __restrict__ s2,
                                                    const float* __restrict__ c2,
                                                    __half* __restrict__ We, int R) {
  __shared__ float As[64][68];
  __shared__ float Bs[64][64];
  int t = threadIdx.x;
  int c0 = blockIdx.x * 64;
  int r0 = blockIdx.y * 64;
  int tx = t & 15, ty = t >> 4;
  float acc[4][4];
#pragma unroll
  for (int i = 0; i < 4; ++i)
#pragma unroll
    for (int j = 0; j < 4; ++j) acc[i][j] = 0.f;
  for (int kc = 0; kc < 2; ++kc) {
    int k0 = kc * 64;
    __syncthreads();
#pragma unroll
    for (int j = 0; j < 2; ++j) {  // A: 64 rows x 64 k (fp16 -> f32)
      int idx = j * 256 + t;
      int mm = idx >> 3, k8 = (idx & 7) * 8;
      int r = r0 + mm;
      uint4 u = make_uint4(0, 0, 0, 0);
      if (r < R) u = *(const uint4*)&T[(size_t)r * 128 + k0 + k8];
      const __half* hp = (const __half*)&u;
      *(float4*)&As[mm][k8] =
          make_float4(__half2float(hp[0]), __half2float(hp[1]), __half2float(hp[2]), __half2float(hp[3]));
      *(float4*)&As[mm][k8 + 4] =
          make_float4(__half2float(hp[4]), __half2float(hp[5]), __half2float(hp[6]), __half2float(hp[7]));
    }
#pragma unroll
    for (int j = 0; j < 4; ++j) {  // B: 64 k x 64 cols
      int f4 = j * 256 + t;
      int kk = f4 >> 4, nq = (f4 & 15) * 4;
      *(float4*)&Bs[kk][nq] = *(const float4*)&W2[(size_t)(k0 + kk) * 1024 + c0 + nq];
    }
    __syncthreads();
#pragma unroll 4
    for (int kq = 0; kq < 16; ++kq) {
      float av[4][4], bv[4][4];
#pragma unroll
      for (int i = 0; i < 4; ++i) {
        float4 q = *(float4*)&As[ty * 4 + i][kq * 4];
        av[i][0] = q.x; av[i][1] = q.y; av[i][2] = q.z; av[i][3] = q.w;
        float4 p = *(float4*)&Bs[kq * 4 + i][tx * 4];
        bv[i][0] = p.x; bv[i][1] = p.y; bv[i][2] = p.z; bv[i][3] = p.w;
      }
#pragma unroll
      for (int kk = 0; kk < 4; ++kk)
#pragma unroll
        for (int i = 0; i < 4; ++i)
#pragma unroll
          for (int j = 0; j < 4; ++j) acc[i][j] += av[i][kk] * bv[kk][j];
    }
  }
  int cbase = c0 + tx * 4;
  float4 b4 = *(const float4*)&b2[cbase];
  float4 s4 = *(const float4*)&s2[cbase];
  float4 c4 = *(const float4*)&c2[cbase];
#pragma unroll
  for (int i = 0; i < 4; ++i) {
    int r = r0 + ty * 4 + i;
    if (r >= R) continue;
    float o0 = (acc[i][0] + b4.x) * s4.x + c4.x;
    float o1 = (acc[i][1] + b4.y) * s4.y + c4.y;
    float o2 = (acc[i][2] + b4.z) * s4.z + c4.z;
    float o3 = (acc[i][3] + b4.w) * s4.w + c4.w;
    ushort4 u;
    u.x = __half_as_ushort(__float2half(o0));
    u.y = __half_as_ushort(__float2half(o1));
    u.z = __half_as_ushort(__float2half(o2));
    u.w = __half_as_ushort(__float2half(o3));
    *(ushort4*)((unsigned short*)We + (size_t)r * 1024 + cbase) = u;
  }
}

// ---- full path: msg[e,o] = sum_i h[src,i]*We[e,i*32+o], scatter to m[dst] ----
__global__ __launch_bounds__(256) void msg_kernel(const __half* __restrict__ We,
                                                  const float* __restrict__ h,
                                                  const int* __restrict__ src,
                                                  const int* __restrict__ dst,
                                                  float* __restrict__ m, int E) {
  int gid = blockIdx.x * 256 + threadIdx.x;
  int e = gid >> 2;
  if (e >= E) return;
  int sub = gid & 3;
  int sn = src[e], dn = dst[e];
  float hv[32];
#pragma unroll
  for (int q = 0; q < 8; ++q) {
    float4 v = *(const float4*)&h[(size_t)sn * 32 + q * 4];
    hv[q * 4] = v.x; hv[q * 4 + 1] = v.y; hv[q * 4 + 2] = v.z; hv[q * 4 + 3] = v.w;
  }
  float acc[8];
#pragma unroll
  for (int j = 0; j < 8; ++j) acc[j] = 0.f;
  const __half* wp = We + (size_t)e * 1024 + sub * 8;
#pragma unroll
  for (int i = 0; i < 32; ++i) {
    uint4 u = *(const uint4*)(wp + i * 32);
    const __half* hp = (const __half*)&u;
    float hi = hv[i];
    acc[0] += hi * __half2float(hp[0]);
    acc[1] += hi * __half2float(hp[1]);
    acc[2] += hi * __half2float(hp[2]);
    acc[3] += hi * __half2float(hp[3]);
    acc[4] += hi * __half2float(hp[4]);
    acc[5] += hi * __half2float(hp[5]);
    acc[6] += hi * __half2float(hp[6]);
    acc[7] += hi * __half2float(hp[7]);
  }
  float* mp = m + (size_t)dn * 32 + sub * 8;
#pragma unroll
  for (int j = 0; j < 8; ++j) atomicAdd(&mp[j], acc[j]);
}

// ---- compact path: recompute We on the fly (16 edges/block, 2 groups of 8) ----
__global__ __launch_bounds__(256) void msg_fused(const __half* __restrict__ T,
                                                 const float* __restrict__ W2,
                                                 const float* __restrict__ b2,
                                                 const float* __restrict__ s2,
                                                 const float* __restrict__ c2,
                                                 const float* __restrict__ h,
                                                 const int* __restrict__ src,
                                                 const int* __restrict__ dst,
                                                 float* __restrict__ m, int E) {
  __shared__ float tt[16][128];
  __shared__ float hs[16][32];
  __shared__ float w2s[8][1024];
  __shared__ float b2l[1024], s2l[1024], c2l[1024];
  int t = threadIdx.x;
  for (int i = t; i < 1024; i += 256) { b2l[i] = b2[i]; s2l[i] = s2[i]; c2l[i] = c2[i]; }
  int e0 = blockIdx.x * 16;
  int le = t >> 5, o = t & 31;
  int eA = e0 + le, eB = e0 + 8 + le;
  bool vA = eA < E, vB = eB < E;
  int snA = vA ? src[eA] : 0, dnA = vA ? dst[eA] : 0;
  int snB = vB ? src[eB] : 0, dnB = vB ? dst[eB] : 0;
  {
    int rr = t >> 4, g8 = (t & 15) * 8;
    int ge = e0 + rr;
    uint4 u = make_uint4(0, 0, 0, 0);
    if (ge < E) u = *(const uint4*)&T[(size_t)ge * 128 + g8];
    const __half* hp = (const __half*)&u;
#pragma unroll
    for (int q = 0; q < 8; ++q) tt[rr][g8 + q] = __half2float(hp[q]);
  }
  hs[le][o] = vA ? h[(size_t)snA * 32 + o] : 0.f;
  hs[8 + le][o] = vB ? h[(size_t)snB * 32 + o] : 0.f;
  float rawA[32], rawB[32];
#pragma unroll
  for (int i = 0; i < 32; ++i) { rawA[i] = 0.f; rawB[i] = 0.f; }
  for (int kc = 0; kc < 16; ++kc) {
    __syncthreads();
#pragma unroll
    for (int j = 0; j < 8; ++j) {
      int idx = j * 256 + t;
      int rr = idx >> 8, cc = (idx & 255) * 4;
      *(float4*)&w2s[rr][cc] = *(const float4*)&W2[(size_t)(kc * 8 + rr) * 1024 + cc];
    }
    __syncthreads();
#pragma unroll
    for (int kk = 0; kk < 8; ++kk) {
      float tvA = tt[le][kc * 8 + kk], tvB = tt[8 + le][kc * 8 + kk];
#pragma unroll
      for (int i = 0; i < 32; ++i) {
        float w = w2s[kk][i * 32 + o];
        rawA[i] += tvA * w;
        rawB[i] += tvB * w;
      }
    }
  }
  float accA = 0.f, accB = 0.f;
#pragma unroll
  for (int i = 0; i < 32; ++i) {
    int io = i * 32 + o;
    float wA = (rawA[i] + b2l[io]) * s2l[io] + c2l[io];
    accA += hs[le][i] * wA;
    float wB = (rawB[i] + b2l[io]) * s2l[io] + c2l[io];
    accB += hs[8 + le][i] * wB;
  }
  if (vA) atomicAdd(&m[(size_t)dnA * 32 + o], accA);
  if (vB) atomicAdd(&m[(size_t)dnB * 32 + o], accB);
}

// ---- GRU cell ----
__global__ __launch_bounds__(256) void gru_kernel(const float* __restrict__ m,
                                                  const float* __restrict__ inv_den,
                                                  const float* __restrict__ h_in,
                                                  const float* __restrict__ Wih,
                                                  const float* __restrict__ Whh,
                                                  const float* __restrict__ bih,
                                                  const float* __restrict__ bhh,
                                                  float* __restrict__ h_out, int N) {
  __shared__ float WT[32 * 96], UT[32 * 96];
  for (int idx = threadIdx.x; idx < 96 * 32; idx += 256) {
    int j = idx / 32, i = idx % 32;
    WT[i * 96 + j] = Wih[idx];
    UT[i * 96 + j] = Whh[idx];
  }
  __syncthreads();
  int gid = blockIdx.x * 256 + threadIdx.x;
  if (gid >= N * 32) return;
  int n = gid >> 5, o = gid & 31;
  float inv = inv_den[n];
  float air = 0.f, aiz = 0.f, ain = 0.f, ahr = 0.f, ahz = 0.f, ahn = 0.f;
#pragma unroll
  for (int i = 0; i < 32; ++i) {
    float mi = m[(size_t)n * 32 + i] * inv;
    float hi = h_in[(size_t)n * 32 + i];
    const float* w = &WT[i * 96 + o];
    const float* u = &UT[i * 96 + o];
    air += mi * w[0];  aiz += mi * w[32];  ain += mi * w[64];
    ahr += hi * u[0];  ahz += hi * u[32];  ahn += hi * u[64];
  }
  float r = 1.f / (1.f + expf(-(air + bih[o] + ahr + bhh[o])));
  float z = 1.f / (1.f + expf(-(aiz + bih[o + 32] + ahz + bhh[o + 32])));
  float ng = tanhf(ain + bih[o + 64] + r * (ahn + bhh[o + 64]));
  h_out[gid] = (1.f - z) * ng + z * h_in[(size_t)n * 32 + o];
}

extern "C" void kernel_launch(void* const* d_in, const int* in_sizes, int n_in,
                              void* d_out, int out_size, void* d_ws, size_t ws_size,
                              hipStream_t stream) {
  const float* x_node = (const float*)d_in[0];
  const float* x_edge = (const float*)d_in[1];
  const int* src = (const int*)d_in[2];
  const int* dst = (const int*)d_in[3];
  const float* bn_n_g = (const float*)d_in[4];
  const float* bn_n_b = (const float*)d_in[5];
  const float* node_W = (const float*)d_in[6];
  const float* node_b = (const float*)d_in[7];
  const float* bn_e_g = (const float*)d_in[8];
  const float* bn_e_b = (const float*)d_in[9];
  const float* edge_W = (const float*)d_in[10];
  const float* edge_b = (const float*)d_in[11];
  const float* en_W1 = (const float*)d_in[12];
  const float* en_b1 = (const float*)d_in[13];
  const float* en_bn1_g = (const float*)d_in[14];
  const float* en_bn1_b = (const float*)d_in[15];
  const float* en_W2 = (const float*)d_in[16];
  const float* en_b2 = (const float*)d_in[17];
  const float* en_bn2_g = (const float*)d_in[18];
  const float* en_bn2_b = (const float*)d_in[19];
  const float* gWih = (const float*)d_in[20];
  const float* gWhh = (const float*)d_in[21];
  const float* gbih = (const float*)d_in[22];
  const float* gbhh = (const float*)d_in[23];
  float* out = (float*)d_out;

  const size_t SZ_WE = 204800000;                 // NE*1024*2 (fp16)
  const size_t CORE = 33523968;                   // everything else
  const size_t FULL_NEED = SZ_WE + CORE;          // 238,323,968
  bool full = (ws_size >= FULL_NEED);

  char* ws = (char*)d_ws;
  size_t base = full ? SZ_WE : 0;
  __half* We   = (__half*)(ws + 0);               // full path only
  __half* Tt   = (__half*)(ws + base);            // 25,600,000
  float* h_a   = (float*)(ws + base + 25600000);  //  2,560,000
  float* h_b   = (float*)(ws + base + 28160000);  //  2,560,000
  float* m_buf = (float*)(ws + base + 30720000);  //  2,560,000
  float* inv_den = (float*)(ws + base + 33280000);//     80,000
  // zeroed region (one zerok per launch): 147,584 B = 36,896 floats
  float* zbase = (float*)(ws + base + 33360000);
  float* deg   = zbase;                           // 20000 f
  float* S     = zbase + 20000;                   // 16384 f
  float* tsum  = zbase + 36384;                   // 128 f
  float* sxs   = zbase + 36512;                   // 128 f (110 used)
  float* nstat = zbase + 36640;                   // 128 f (80 used)
  float* estat = zbase + 36768;                   // 128 f (20 used)
  // params (fully overwritten each launch)
  float* par = (float*)(ws + base + 33507584);
  float* ns = par + 0;    float* nc = par + 64;
  float* es = par + 128;  float* ec = par + 192;
  float* s1 = par + 256;  float* c1 = par + 384;
  float* wc = par + 512;                          // 1280 f
  float* bcb = par + 1792;                        // 128 f
  float* s2 = par + 1920; float* c2 = par + 2944; // 1024 f each

  zerok<<<(36896 + 255) / 256, 256, 0, stream>>>(zbase, 36896);

  colstats<40><<<200, 256, 0, stream>>>(x_node, nstat, NN * 40);
  colstats<10><<<256, 256, 0, stream>>>(x_edge, estat, NE * 10);
  deg_kernel<<<(NE + 255) / 256, 256, 0, stream>>>(dst, deg, NE);
  finalize_bn<<<1, 64, 0, stream>>>(nstat, bn_n_g, bn_n_b, ns, nc, 40, 1.f / NN);
  finalize_bn<<<1, 64, 0, stream>>>(estat, bn_e_g, bn_e_b, es, ec, 10, 1.f / NE);
  invden_kernel<<<(NN + 255) / 256, 256, 0, stream>>>(deg, inv_den, NN);

  fold_w1<<<1, 256, 0, stream>>>(edge_W, edge_b, en_W1, en_b1, wc, bcb);
  sx_kernel<<<128, 64, 0, stream>>>(x_edge, es, ec, sxs, NE);
  bn1_from_sx<<<1, 128, 0, stream>>>(sxs, wc, bcb, en_bn1_g, en_bn1_b, s1, c1);
  t_kernel<<<(NE * 128 + 255) / 256, 256, 0, stream>>>(x_edge, es, ec, wc, bcb, s1, c1, Tt, NE);
  tsq_kernel<<<64, 256, 0, stream>>>(Tt, S, tsum, NE);
  bn2_from_s<<<4, 256, 0, stream>>>(S, tsum, en_W2, en_b2, en_bn2_g, en_bn2_b, s2, c2);

  embed_gemm<40, 32><<<(NN * 32 + 255) / 256, 256, 0, stream>>>(x_node, ns, nc, node_W, node_b, h_a, NN);

  if (full) {
    dim3 g(16, (NE + 63) / 64);
    gemm2_kernel<<<g, 256, 0, stream>>>(Tt, en_W2, en_b2, s2, c2, We, NE);
  }

  const float* hin = h_a;
  for (int l = 0; l < 3; ++l) {
    float* hout = (l == 0) ? h_b : (l == 1) ? h_a : out;
    zerok<<<(NN * 32 + 255) / 256, 256, 0, stream>>>(m_buf, NN * 32);
    if (full) {
      msg_kernel<<<(NE * 4 + 255) / 256, 256, 0, stream>>>(We, hin, src, dst, m_buf, NE);
    } else {
      msg_fused<<<(NE + 15) / 16, 256, 0, stream>>>(Tt, en_W2, en_b2, s2, c2, hin, src, dst, m_buf, NE);
    }
    gru_kernel<<<(NN * 32 + 255) / 256, 256, 0, stream>>>(m_buf, inv_den, hin, gWih, gWhh,
                                                          gbih, gbhh, hout, NN);
    hin = hout;
  }
}

// Round 3
// 1032.699 us; speedup vs baseline: 1.6420x; 1.6420x over previous
//
#include <hip/hip_runtime.h>
#include <hip/hip_fp16.h>

#define NN 20000
#define NE 100000

typedef _Float16 f16x8 __attribute__((ext_vector_type(8)));
typedef float f32x4 __attribute__((ext_vector_type(4)));

__device__ __forceinline__ float wred(float v) {
#pragma unroll
  for (int k = 1; k < 64; k <<= 1) v += __shfl_xor(v, k);
  return v;
}

__global__ void zerok(float* __restrict__ p, int n) {
  int i = blockIdx.x * 256 + threadIdx.x;
  if (i < n) p[i] = 0.f;
}

// ---- per-column sum / sumsq over [R, C] fp32 ----
template <int C>
__global__ void colstats(const float* __restrict__ x, float* __restrict__ stat, int total) {
  __shared__ float ls[2 * C];
  for (int i = threadIdx.x; i < 2 * C; i += blockDim.x) ls[i] = 0.f;
  __syncthreads();
  for (int idx = blockIdx.x * blockDim.x + threadIdx.x; idx < total; idx += gridDim.x * blockDim.x) {
    float v = x[idx];
    int c = idx % C;
    atomicAdd(&ls[c], v);
    atomicAdd(&ls[C + c], v * v);
  }
  __syncthreads();
  for (int i = threadIdx.x; i < 2 * C; i += blockDim.x) atomicAdd(&stat[i], ls[i]);
}

__global__ void finalize_bn(const float* __restrict__ stat, const float* __restrict__ g,
                            const float* __restrict__ b, float* __restrict__ s_out,
                            float* __restrict__ c_out, int C, float invR) {
  int c = blockIdx.x * blockDim.x + threadIdx.x;
  if (c >= C) return;
  float mean = stat[c] * invR;
  float var = fmaxf(stat[C + c] * invR - mean * mean, 0.f);
  float sc = g[c] * rsqrtf(var + 1e-5f);
  s_out[c] = sc;
  c_out[c] = b[c] - mean * sc;
}

__global__ void deg_kernel(const int* __restrict__ dst, float* __restrict__ deg, int E) {
  int e = blockIdx.x * blockDim.x + threadIdx.x;
  if (e < E) atomicAdd(&deg[dst[e]], 1.f);
}

__global__ void invden_kernel(const float* __restrict__ deg, float* __restrict__ inv, int N) {
  int n = blockIdx.x * blockDim.x + threadIdx.x;
  if (n < N) inv[n] = 1.f / fmaxf(deg[n], 1.f);
}

// ---- Wc[10,128] = edge_W @ en_W1 ; bc[128] = edge_b @ en_W1 + en_b1 ----
__global__ void fold_w1(const float* __restrict__ edge_W, const float* __restrict__ edge_b,
                        const float* __restrict__ en_W1, const float* __restrict__ en_b1,
                        float* __restrict__ Wc, float* __restrict__ bc) {
  int t = threadIdx.x;
  for (int idx = t; idx < 1280; idx += 256) {
    int bq = idx >> 7, j = idx & 127;
    float a = 0.f;
    for (int q = 0; q < 128; ++q) a += edge_W[bq * 128 + q] * en_W1[q * 128 + j];
    Wc[idx] = a;
  }
  if (t < 128) {
    float a = en_b1[t];
    for (int q = 0; q < 128; ++q) a += edge_b[q] * en_W1[q * 128 + t];
    bc[t] = a;
  }
}

// ---- Sx[10][10] + xsum[10] over xb = x*es+ec ----
__global__ __launch_bounds__(64) void sx_kernel(const float* __restrict__ x,
                                                const float* __restrict__ es,
                                                const float* __restrict__ ec,
                                                float* __restrict__ sxs, int E) {
  float s[10][10], xs[10], esl[10], ecl[10];
#pragma unroll
  for (int a = 0; a < 10; ++a) {
    xs[a] = 0.f; esl[a] = es[a]; ecl[a] = ec[a];
#pragma unroll
    for (int b = 0; b < 10; ++b) s[a][b] = 0.f;
  }
  for (int e = blockIdx.x * 64 + threadIdx.x; e < E; e += gridDim.x * 64) {
    float xb[10];
#pragma unroll
    for (int q = 0; q < 10; ++q) xb[q] = x[(size_t)e * 10 + q] * esl[q] + ecl[q];
#pragma unroll
    for (int a = 0; a < 10; ++a) {
      xs[a] += xb[a];
#pragma unroll
      for (int b = 0; b < 10; ++b) s[a][b] += xb[a] * xb[b];
    }
  }
#pragma unroll
  for (int a = 0; a < 10; ++a) {
    float r = wred(xs[a]);
    if (threadIdx.x == 0) atomicAdd(&sxs[100 + a], r);
#pragma unroll
    for (int b = 0; b < 10; ++b) {
      float r2 = wred(s[a][b]);
      if (threadIdx.x == 0) atomicAdd(&sxs[a * 10 + b], r2);
    }
  }
}

// ---- BN1 scale/shift from Sx quadratic form ----
__global__ void bn1_from_sx(const float* __restrict__ sxs, const float* __restrict__ Wc,
                            const float* __restrict__ bc, const float* __restrict__ g,
                            const float* __restrict__ b, float* __restrict__ s1,
                            float* __restrict__ c1) {
  int j = threadIdx.x;  // 128
  float w[10];
#pragma unroll
  for (int q = 0; q < 10; ++q) w[q] = Wc[q * 128 + j];
  float d = 0.f;
#pragma unroll
  for (int q = 0; q < 10; ++q) d += sxs[100 + q] * w[q];
  float qq = 0.f;
#pragma unroll
  for (int a = 0; a < 10; ++a) {
    float p = 0.f;
#pragma unroll
    for (int bq = 0; bq < 10; ++bq) p += sxs[a * 10 + bq] * w[bq];
    qq += w[a] * p;
  }
  float invE = 1.f / (float)NE;
  float bias = bc[j];
  float mean = d * invE + bias;
  float m2 = (qq + 2.f * bias * d) * invE + bias * bias;
  float var = fmaxf(m2 - mean * mean, 0.f);
  float sc = g[j] * rsqrtf(var + 1e-5f);
  s1[j] = sc;
  c1[j] = b[j] - mean * sc;
}

// ---- t[e,j] = leaky(bn1(xb@Wc + bc))  -> fp16 [NE,128] ----
__global__ __launch_bounds__(256) void t_kernel(const float* __restrict__ x,
                                                const float* __restrict__ es,
                                                const float* __restrict__ ec,
                                                const float* __restrict__ Wc,
                                                const float* __restrict__ bcb,
                                                const float* __restrict__ s1,
                                                const float* __restrict__ c1,
                                                __half* __restrict__ T, int E) {
  __shared__ float Wcl[1280], bcl[128], s1l[128], c1l[128], esl[10], ecl[10];
  for (int i = threadIdx.x; i < 1280; i += 256) Wcl[i] = Wc[i];
  if (threadIdx.x < 128) {
    bcl[threadIdx.x] = bcb[threadIdx.x];
    s1l[threadIdx.x] = s1[threadIdx.x];
    c1l[threadIdx.x] = c1[threadIdx.x];
  }
  if (threadIdx.x < 10) { esl[threadIdx.x] = es[threadIdx.x]; ecl[threadIdx.x] = ec[threadIdx.x]; }
  __syncthreads();
  int gid = blockIdx.x * 256 + threadIdx.x;
  if (gid >= E * 128) return;
  int r = gid >> 7, j = gid & 127;
  float acc = bcl[j];
#pragma unroll
  for (int q = 0; q < 10; ++q) acc += (x[(size_t)r * 10 + q] * esl[q] + ecl[q]) * Wcl[q * 128 + j];
  float tv = acc * s1l[j] + c1l[j];
  tv = tv > 0.f ? tv : 0.8f * tv;
  T[gid] = __float2half(tv);
}

// ---- S[128][128] = sum_e t t^T ; tsum[128] = sum_e t ----
__global__ __launch_bounds__(256) void tsq_kernel(const __half* __restrict__ T,
                                                  float* __restrict__ S,
                                                  float* __restrict__ tsum, int E) {
  __shared__ float tt[16][128];
  int t = threadIdx.x;
  int ta = t >> 4, tb = t & 15;
  float acc[8][8];
#pragma unroll
  for (int a = 0; a < 8; ++a)
#pragma unroll
    for (int b = 0; b < 8; ++b) acc[a][b] = 0.f;
  float tsl = 0.f;
  int per = (E + gridDim.x - 1) / gridDim.x;
  int e0 = blockIdx.x * per;
  int e1 = min(E, e0 + per);
  for (int ec = e0; ec < e1; ec += 16) {
    __syncthreads();
    int rr = t >> 4, g8 = (t & 15) * 8;
    int e = ec + rr;
    uint4 u = make_uint4(0, 0, 0, 0);
    if (e < e1) u = *(const uint4*)&T[(size_t)e * 128 + g8];
    const __half* hp = (const __half*)&u;
#pragma unroll
    for (int q = 0; q < 8; ++q) tt[rr][g8 + q] = __half2float(hp[q]);
    __syncthreads();
    if (t < 128) {
#pragma unroll
      for (int r2 = 0; r2 < 16; ++r2) tsl += tt[r2][t];
    }
#pragma unroll
    for (int ee = 0; ee < 16; ++ee) {
      float va[8], vb[8];
#pragma unroll
      for (int q = 0; q < 8; ++q) { va[q] = tt[ee][ta * 8 + q]; vb[q] = tt[ee][tb * 8 + q]; }
#pragma unroll
      for (int a = 0; a < 8; ++a)
#pragma unroll
        for (int b = 0; b < 8; ++b) acc[a][b] += va[a] * vb[b];
    }
  }
#pragma unroll
  for (int a = 0; a < 8; ++a)
#pragma unroll
    for (int b = 0; b < 8; ++b) atomicAdd(&S[(ta * 8 + a) * 128 + tb * 8 + b], acc[a][b]);
  if (t < 128) atomicAdd(&tsum[t], tsl);
}

// ---- parallel BN2: one wave per output column io; S staged in LDS ----
// s2[io] = g*rsqrt(var+eps);  c2p[io] = b - (mean_raw + b2[io])*s2[io]
// so that We = raw*s2 + c2p  (raw = t@W2, NO bias)
__global__ __launch_bounds__(256) void bn2p(const float* __restrict__ S,
                                            const float* __restrict__ tsum,
                                            const float* __restrict__ W2,
                                            const float* __restrict__ b2,
                                            const float* __restrict__ g,
                                            const float* __restrict__ b,
                                            float* __restrict__ s2, float* __restrict__ c2p) {
  __shared__ float Sl[16384];
  __shared__ float tsl[128];
  for (int i = threadIdx.x; i < 16384; i += 256) Sl[i] = S[i];
  if (threadIdx.x < 128) tsl[threadIdx.x] = tsum[threadIdx.x];
  __syncthreads();
  int w = threadIdx.x >> 6, lane = threadIdx.x & 63;
  int io = blockIdx.x * 4 + w;
  float wlo = W2[(size_t)lane * 1024 + io];
  float whi = W2[(size_t)(lane + 64) * 1024 + io];
  float plo = 0.f, phi = 0.f;
#pragma unroll
  for (int a = 0; a < 64; ++a) {
    float wa = __shfl(wlo, a);
    plo += wa * Sl[a * 128 + lane];
    phi += wa * Sl[a * 128 + lane + 64];
  }
#pragma unroll
  for (int a = 0; a < 64; ++a) {
    float wa = __shfl(whi, a);
    plo += wa * Sl[(a + 64) * 128 + lane];
    phi += wa * Sl[(a + 64) * 128 + lane + 64];
  }
  float qq = wred(plo * wlo + phi * whi);
  float d = wred(wlo * tsl[lane] + whi * tsl[lane + 64]);
  if (lane == 0) {
    float invE = 1.f / (float)NE;
    float mean_raw = d * invE;
    float var = fmaxf(qq * invE - mean_raw * mean_raw, 0.f);
    float sc = g[io] * rsqrtf(var + 1e-5f);
    s2[io] = sc;
    c2p[io] = b[io] - (mean_raw + b2[io]) * sc;
  }
}

// ---- repack W2 (f32 [128,1024]) into MFMA B-fragment layout, fp16 ----
// Bp[((cb*4+ks)*64 + lane)*8 + j] = W2[ks*32 + (lane>>4)*8 + j][cb*16 + (lane&15)]
__global__ void repack_w2(const float* __restrict__ W2, unsigned short* __restrict__ Bp) {
  int idx = blockIdx.x * 256 + threadIdx.x;
  if (idx >= 16384) return;
  int cb = idx >> 8;
  int ks = (idx >> 6) & 3;
  int lane = idx & 63;
  int col = cb * 16 + (lane & 15);
  int kbase = ks * 32 + (lane >> 4) * 8;
  unsigned short tmp[8];
#pragma unroll
  for (int j = 0; j < 8; ++j)
    tmp[j] = __half_as_ushort(__float2half(W2[(size_t)(kbase + j) * 1024 + col]));
  *(uint4*)&Bp[(size_t)idx * 8] = *(uint4*)tmp;
}

// ---- MFMA GEMM: We[e,io] = (T[e,:]@W2[:,io])*s2[io] + c2p[io]  -> fp16 ----
// block: 256 thr = 4 waves; 64 rows x 256 cols; wave w -> 64-col slice.
__global__ __launch_bounds__(256) void gemm2_mfma(const __half* __restrict__ T,
                                                  const unsigned short* __restrict__ Bp,
                                                  const float* __restrict__ s2,
                                                  const float* __restrict__ c2p,
                                                  __half* __restrict__ We, int R) {
  int w = threadIdx.x >> 6, lane = threadIdx.x & 63;
  int r0 = blockIdx.y * 64;
  int cb0 = blockIdx.x * 16 + w * 4;  // first 16-col fragment index for this wave
  f32x4 acc[4][4];
#pragma unroll
  for (int i = 0; i < 4; ++i)
#pragma unroll
    for (int j = 0; j < 4; ++j) acc[i][j] = {0.f, 0.f, 0.f, 0.f};
  int arow = lane & 15, kgrp = lane >> 4;
#pragma unroll
  for (int ks = 0; ks < 4; ++ks) {
    f16x8 a[4];
#pragma unroll
    for (int ri = 0; ri < 4; ++ri) {
      int r = r0 + ri * 16 + arow;
      f16x8 av{};
      if (r < R) av = *(const f16x8*)&T[(size_t)r * 128 + ks * 32 + kgrp * 8];
      a[ri] = av;
    }
#pragma unroll
    for (int ci = 0; ci < 4; ++ci) {
      f16x8 bv = *(const f16x8*)&Bp[((size_t)((cb0 + ci) * 4 + ks) * 64 + lane) * 8];
#pragma unroll
      for (int ri = 0; ri < 4; ++ri)
        acc[ri][ci] = __builtin_amdgcn_mfma_f32_16x16x32_f16(a[ri], bv, acc[ri][ci], 0, 0, 0);
    }
  }
#pragma unroll
  for (int ci = 0; ci < 4; ++ci) {
    int col = (cb0 + ci) * 16 + arow;
    float sc = s2[col];
    float cc = c2p[col];
#pragma unroll
    for (int ri = 0; ri < 4; ++ri) {
#pragma unroll
      for (int q = 0; q < 4; ++q) {
        int r = r0 + ri * 16 + kgrp * 4 + q;
        if (r < R)
          We[(size_t)r * 1024 + col] = __float2half(acc[ri][ci][q] * sc + cc);
      }
    }
  }
}

// ---- full path: msg[e,o] = sum_i h[src,i]*We[e,i*32+o], scatter to m[dst] ----
__global__ __launch_bounds__(256) void msg_kernel(const __half* __restrict__ We,
                                                  const float* __restrict__ h,
                                                  const int* __restrict__ src,
                                                  const int* __restrict__ dst,
                                                  float* __restrict__ m, int E) {
  int gid = blockIdx.x * 256 + threadIdx.x;
  int e = gid >> 2;
  if (e >= E) return;
  int sub = gid & 3;
  int sn = src[e], dn = dst[e];
  float hv[32];
#pragma unroll
  for (int q = 0; q < 8; ++q) {
    float4 v = *(const float4*)&h[(size_t)sn * 32 + q * 4];
    hv[q * 4] = v.x; hv[q * 4 + 1] = v.y; hv[q * 4 + 2] = v.z; hv[q * 4 + 3] = v.w;
  }
  float acc[8];
#pragma unroll
  for (int j = 0; j < 8; ++j) acc[j] = 0.f;
  const __half* wp = We + (size_t)e * 1024 + sub * 8;
#pragma unroll
  for (int i = 0; i < 32; ++i) {
    uint4 u = *(const uint4*)(wp + i * 32);
    const __half* hp = (const __half*)&u;
    float hi = hv[i];
    acc[0] += hi * __half2float(hp[0]);
    acc[1] += hi * __half2float(hp[1]);
    acc[2] += hi * __half2float(hp[2]);
    acc[3] += hi * __half2float(hp[3]);
    acc[4] += hi * __half2float(hp[4]);
    acc[5] += hi * __half2float(hp[5]);
    acc[6] += hi * __half2float(hp[6]);
    acc[7] += hi * __half2float(hp[7]);
  }
  float* mp = m + (size_t)dn * 32 + sub * 8;
#pragma unroll
  for (int j = 0; j < 8; ++j) atomicAdd(&mp[j], acc[j]);
}

// ---- compact fallback: recompute We on the fly ----
__global__ __launch_bounds__(256) void msg_fused(const __half* __restrict__ T,
                                                 const float* __restrict__ W2,
                                                 const float* __restrict__ s2,
                                                 const float* __restrict__ c2p,
                                                 const float* __restrict__ h,
                                                 const int* __restrict__ src,
                                                 const int* __restrict__ dst,
                                                 float* __restrict__ m, int E) {
  __shared__ float tt[16][128];
  __shared__ float hs[16][32];
  __shared__ float w2s[8][1024];
  __shared__ float s2l[1024], c2l[1024];
  int t = threadIdx.x;
  for (int i = t; i < 1024; i += 256) { s2l[i] = s2[i]; c2l[i] = c2p[i]; }
  int e0 = blockIdx.x * 16;
  int le = t >> 5, o = t & 31;
  int eA = e0 + le, eB = e0 + 8 + le;
  bool vA = eA < E, vB = eB < E;
  int snA = vA ? src[eA] : 0, dnA = vA ? dst[eA] : 0;
  int snB = vB ? src[eB] : 0, dnB = vB ? dst[eB] : 0;
  {
    int rr = t >> 4, g8 = (t & 15) * 8;
    int ge = e0 + rr;
    uint4 u = make_uint4(0, 0, 0, 0);
    if (ge < E) u = *(const uint4*)&T[(size_t)ge * 128 + g8];
    const __half* hp = (const __half*)&u;
#pragma unroll
    for (int q = 0; q < 8; ++q) tt[rr][g8 + q] = __half2float(hp[q]);
  }
  hs[le][o] = vA ? h[(size_t)snA * 32 + o] : 0.f;
  hs[8 + le][o] = vB ? h[(size_t)snB * 32 + o] : 0.f;
  float rawA[32], rawB[32];
#pragma unroll
  for (int i = 0; i < 32; ++i) { rawA[i] = 0.f; rawB[i] = 0.f; }
  for (int kc = 0; kc < 16; ++kc) {
    __syncthreads();
#pragma unroll
    for (int j = 0; j < 8; ++j) {
      int idx = j * 256 + t;
      int rr = idx >> 8, cc = (idx & 255) * 4;
      *(float4*)&w2s[rr][cc] = *(const float4*)&W2[(size_t)(kc * 8 + rr) * 1024 + cc];
    }
    __syncthreads();
#pragma unroll
    for (int kk = 0; kk < 8; ++kk) {
      float tvA = tt[le][kc * 8 + kk], tvB = tt[8 + le][kc * 8 + kk];
#pragma unroll
      for (int i = 0; i < 32; ++i) {
        float w = w2s[kk][i * 32 + o];
        rawA[i] += tvA * w;
        rawB[i] += tvB * w;
      }
    }
  }
  float accA = 0.f, accB = 0.f;
#pragma unroll
  for (int i = 0; i < 32; ++i) {
    int io = i * 32 + o;
    accA += hs[le][i] * (rawA[i] * s2l[io] + c2l[io]);
    accB += hs[8 + le][i] * (rawB[i] * s2l[io] + c2l[io]);
  }
  if (vA) atomicAdd(&m[(size_t)dnA * 32 + o], accA);
  if (vB) atomicAdd(&m[(size_t)dnB * 32 + o], accB);
}

// ---- node embedding ----
template <int K, int COUT>
__global__ __launch_bounds__(256) void embed_gemm(const float* __restrict__ x,
                                                  const float* __restrict__ s,
                                                  const float* __restrict__ c,
                                                  const float* __restrict__ W,
                                                  const float* __restrict__ bias,
                                                  float* __restrict__ out, int R) {
  __shared__ float Wl[K * COUT];
  __shared__ float sl[K], cl[K];
  for (int i = threadIdx.x; i < K * COUT; i += 256) Wl[i] = W[i];
  for (int i = threadIdx.x; i < K; i += 256) { sl[i] = s[i]; cl[i] = c[i]; }
  __syncthreads();
  int gid = blockIdx.x * 256 + threadIdx.x;
  if (gid >= R * COUT) return;
  int r = gid / COUT, j = gid % COUT;
  float acc = bias[j];
#pragma unroll
  for (int k = 0; k < K; ++k) acc += (x[(size_t)r * K + k] * sl[k] + cl[k]) * Wl[k * COUT + j];
  out[gid] = acc;
}

// ---- GRU cell ----
__global__ __launch_bounds__(256) void gru_kernel(const float* __restrict__ m,
                                                  const float* __restrict__ inv_den,
                                                  const float* __restrict__ h_in,
                                                  const float* __restrict__ Wih,
                                                  const float* __restrict__ Whh,
                                                  const float* __restrict__ bih,
                                                  const float* __restrict__ bhh,
                                                  float* __restrict__ h_out, int N) {
  __shared__ float WT[32 * 96], UT[32 * 96];
  for (int idx = threadIdx.x; idx < 96 * 32; idx += 256) {
    int j = idx / 32, i = idx % 32;
    WT[i * 96 + j] = Wih[idx];
    UT[i * 96 + j] = Whh[idx];
  }
  __syncthreads();
  int gid = blockIdx.x * 256 + threadIdx.x;
  if (gid >= N * 32) return;
  int n = gid >> 5, o = gid & 31;
  float inv = inv_den[n];
  float air = 0.f, aiz = 0.f, ain = 0.f, ahr = 0.f, ahz = 0.f, ahn = 0.f;
#pragma unroll
  for (int i = 0; i < 32; ++i) {
    float mi = m[(size_t)n * 32 + i] * inv;
    float hi = h_in[(size_t)n * 32 + i];
    const float* w = &WT[i * 96 + o];
    const float* u = &UT[i * 96 + o];
    air += mi * w[0];  aiz += mi * w[32];  ain += mi * w[64];
    ahr += hi * u[0];  ahz += hi * u[32];  ahn += hi * u[64];
  }
  float r = 1.f / (1.f + expf(-(air + bih[o] + ahr + bhh[o])));
  float z = 1.f / (1.f + expf(-(aiz + bih[o + 32] + ahz + bhh[o + 32])));
  float ng = tanhf(ain + bih[o + 64] + r * (ahn + bhh[o + 64]));
  h_out[gid] = (1.f - z) * ng + z * h_in[(size_t)n * 32 + o];
}

extern "C" void kernel_launch(void* const* d_in, const int* in_sizes, int n_in,
                              void* d_out, int out_size, void* d_ws, size_t ws_size,
                              hipStream_t stream) {
  const float* x_node = (const float*)d_in[0];
  const float* x_edge = (const float*)d_in[1];
  const int* src = (const int*)d_in[2];
  const int* dst = (const int*)d_in[3];
  const float* bn_n_g = (const float*)d_in[4];
  const float* bn_n_b = (const float*)d_in[5];
  const float* node_W = (const float*)d_in[6];
  const float* node_b = (const float*)d_in[7];
  const float* bn_e_g = (const float*)d_in[8];
  const float* bn_e_b = (const float*)d_in[9];
  const float* edge_W = (const float*)d_in[10];
  const float* edge_b = (const float*)d_in[11];
  const float* en_W1 = (const float*)d_in[12];
  const float* en_b1 = (const float*)d_in[13];
  const float* en_bn1_g = (const float*)d_in[14];
  const float* en_bn1_b = (const float*)d_in[15];
  const float* en_W2 = (const float*)d_in[16];
  const float* en_b2 = (const float*)d_in[17];
  const float* en_bn2_g = (const float*)d_in[18];
  const float* en_bn2_b = (const float*)d_in[19];
  const float* gWih = (const float*)d_in[20];
  const float* gWhh = (const float*)d_in[21];
  const float* gbih = (const float*)d_in[22];
  const float* gbhh = (const float*)d_in[23];
  float* out = (float*)d_out;

  const size_t SZ_WE = 204800000;                 // NE*1024*2 (fp16)
  const size_t CORE = 33785600;
  const size_t FULL_NEED = SZ_WE + CORE;          // 238,585,600
  bool full = (ws_size >= FULL_NEED);

  char* ws = (char*)d_ws;
  size_t base = full ? SZ_WE : 0;
  __half* We   = (__half*)(ws + 0);               // full path only
  __half* Tt   = (__half*)(ws + base);            // 25,600,000
  float* h_a   = (float*)(ws + base + 25600000);  //  2,560,000
  float* h_b   = (float*)(ws + base + 28160000);  //  2,560,000
  float* m_buf = (float*)(ws + base + 30720000);  //  2,560,000
  float* inv_den = (float*)(ws + base + 33280000);//     80,000
  // zeroed region: 36,896 floats = 147,584 B
  float* zbase = (float*)(ws + base + 33360000);
  float* deg   = zbase;                           // 20000 f
  float* S     = zbase + 20000;                   // 16384 f
  float* tsum  = zbase + 36384;                   // 128 f
  float* sxs   = zbase + 36512;                   // 128 f (110 used)
  float* nstat = zbase + 36640;                   // 128 f (80 used)
  float* estat = zbase + 36768;                   // 128 f (20 used)
  // params (fully overwritten each launch)
  float* par = (float*)(ws + base + 33507584);
  float* ns = par + 0;    float* nc = par + 64;
  float* es = par + 128;  float* ec = par + 192;
  float* s1 = par + 256;  float* c1 = par + 384;
  float* wc = par + 512;                          // 1280 f
  float* bcb = par + 1792;                        // 128 f
  float* s2 = par + 1920; float* c2p = par + 2944;// 1024 f each
  unsigned short* Bp = (unsigned short*)(ws + base + 33523456);  // 262,144 B

  zerok<<<(36896 + 255) / 256, 256, 0, stream>>>(zbase, 36896);

  colstats<40><<<200, 256, 0, stream>>>(x_node, nstat, NN * 40);
  colstats<10><<<256, 256, 0, stream>>>(x_edge, estat, NE * 10);
  deg_kernel<<<(NE + 255) / 256, 256, 0, stream>>>(dst, deg, NE);
  finalize_bn<<<1, 64, 0, stream>>>(nstat, bn_n_g, bn_n_b, ns, nc, 40, 1.f / NN);
  finalize_bn<<<1, 64, 0, stream>>>(estat, bn_e_g, bn_e_b, es, ec, 10, 1.f / NE);
  invden_kernel<<<(NN + 255) / 256, 256, 0, stream>>>(deg, inv_den, NN);

  fold_w1<<<1, 256, 0, stream>>>(edge_W, edge_b, en_W1, en_b1, wc, bcb);
  sx_kernel<<<128, 64, 0, stream>>>(x_edge, es, ec, sxs, NE);
  bn1_from_sx<<<1, 128, 0, stream>>>(sxs, wc, bcb, en_bn1_g, en_bn1_b, s1, c1);
  t_kernel<<<(NE * 128 + 255) / 256, 256, 0, stream>>>(x_edge, es, ec, wc, bcb, s1, c1, Tt, NE);
  tsq_kernel<<<256, 256, 0, stream>>>(Tt, S, tsum, NE);
  bn2p<<<256, 256, 0, stream>>>(S, tsum, en_W2, en_b2, en_bn2_g, en_bn2_b, s2, c2p);

  embed_gemm<40, 32><<<(NN * 32 + 255) / 256, 256, 0, stream>>>(x_node, ns, nc, node_W, node_b, h_a, NN);

  if (full) {
    repack_w2<<<64, 256, 0, stream>>>(en_W2, Bp);
    dim3 g(4, (NE + 63) / 64);
    gemm2_mfma<<<g, 256, 0, stream>>>(Tt, Bp, s2, c2p, We, NE);
  }

  const float* hin = h_a;
  for (int l = 0; l < 3; ++l) {
    float* hout = (l == 0) ? h_b : (l == 1) ? h_a : out;
    zerok<<<(NN * 32 + 255) / 256, 256, 0, stream>>>(m_buf, NN * 32);
    if (full) {
      msg_kernel<<<(NE * 4 + 255) / 256, 256, 0, stream>>>(We, hin, src, dst, m_buf, NE);
    } else {
      msg_fused<<<(NE + 15) / 16, 256, 0, stream>>>(Tt, en_W2, s2, c2p, hin, src, dst, m_buf, NE);
    }
    gru_kernel<<<(NN * 32 + 255) / 256, 256, 0, stream>>>(m_buf, inv_den, hin, gWih, gWhh,
                                                          gbih, gbhh, hout, NN);
    hin = hout;
  }
}

// Round 4
// 816.079 us; speedup vs baseline: 2.0779x; 1.2654x over previous
//
#include <hip/hip_runtime.h>
#include <hip/hip_fp16.h>

#define NN 20000
#define NE 100000
#define TSQ_NB 512

typedef _Float16 f16x8 __attribute__((ext_vector_type(8)));
typedef float f32x4 __attribute__((ext_vector_type(4)));

__device__ __forceinline__ float wred(float v) {
#pragma unroll
  for (int k = 1; k < 64; k <<= 1) v += __shfl_xor(v, k);
  return v;
}

__global__ void zerok(float* __restrict__ p, int n) {
  int i = blockIdx.x * 256 + threadIdx.x;
  if (i < n) p[i] = 0.f;
}

// ---- per-column sum / sumsq over [R, C] fp32 ----
template <int C>
__global__ void colstats(const float* __restrict__ x, float* __restrict__ stat, int total) {
  __shared__ float ls[2 * C];
  for (int i = threadIdx.x; i < 2 * C; i += blockDim.x) ls[i] = 0.f;
  __syncthreads();
  for (int idx = blockIdx.x * blockDim.x + threadIdx.x; idx < total; idx += gridDim.x * blockDim.x) {
    float v = x[idx];
    int c = idx % C;
    atomicAdd(&ls[c], v);
    atomicAdd(&ls[C + c], v * v);
  }
  __syncthreads();
  for (int i = threadIdx.x; i < 2 * C; i += blockDim.x) atomicAdd(&stat[i], ls[i]);
}

__global__ void finalize_bn(const float* __restrict__ stat, const float* __restrict__ g,
                            const float* __restrict__ b, float* __restrict__ s_out,
                            float* __restrict__ c_out, int C, float invR) {
  int c = blockIdx.x * blockDim.x + threadIdx.x;
  if (c >= C) return;
  float mean = stat[c] * invR;
  float var = fmaxf(stat[C + c] * invR - mean * mean, 0.f);
  float sc = g[c] * rsqrtf(var + 1e-5f);
  s_out[c] = sc;
  c_out[c] = b[c] - mean * sc;
}

__global__ void deg_kernel(const int* __restrict__ dst, float* __restrict__ deg, int E) {
  int e = blockIdx.x * blockDim.x + threadIdx.x;
  if (e < E) atomicAdd(&deg[dst[e]], 1.f);
}

__global__ void invden_kernel(const float* __restrict__ deg, float* __restrict__ inv, int N) {
  int n = blockIdx.x * blockDim.x + threadIdx.x;
  if (n < N) inv[n] = 1.f / fmaxf(deg[n], 1.f);
}

// ---- Wc[10,128] = edge_W @ en_W1 ; bc[128] = edge_b @ en_W1 + en_b1 ----
__global__ void fold_w1(const float* __restrict__ edge_W, const float* __restrict__ edge_b,
                        const float* __restrict__ en_W1, const float* __restrict__ en_b1,
                        float* __restrict__ Wc, float* __restrict__ bc) {
  int t = threadIdx.x;
  for (int idx = t; idx < 1280; idx += 256) {
    int bq = idx >> 7, j = idx & 127;
    float a = 0.f;
    for (int q = 0; q < 128; ++q) a += edge_W[bq * 128 + q] * en_W1[q * 128 + j];
    Wc[idx] = a;
  }
  if (t < 128) {
    float a = en_b1[t];
    for (int q = 0; q < 128; ++q) a += edge_b[q] * en_W1[q * 128 + t];
    bc[t] = a;
  }
}

// ---- Sx[10][10] + xsum[10] over xb = x*es+ec ----
__global__ __launch_bounds__(64) void sx_kernel(const float* __restrict__ x,
                                                const float* __restrict__ es,
                                                const float* __restrict__ ec,
                                                float* __restrict__ sxs, int E) {
  float s[10][10], xs[10], esl[10], ecl[10];
#pragma unroll
  for (int a = 0; a < 10; ++a) {
    xs[a] = 0.f; esl[a] = es[a]; ecl[a] = ec[a];
#pragma unroll
    for (int b = 0; b < 10; ++b) s[a][b] = 0.f;
  }
  for (int e = blockIdx.x * 64 + threadIdx.x; e < E; e += gridDim.x * 64) {
    float xb[10];
#pragma unroll
    for (int q = 0; q < 10; ++q) xb[q] = x[(size_t)e * 10 + q] * esl[q] + ecl[q];
#pragma unroll
    for (int a = 0; a < 10; ++a) {
      xs[a] += xb[a];
#pragma unroll
      for (int b = 0; b < 10; ++b) s[a][b] += xb[a] * xb[b];
    }
  }
#pragma unroll
  for (int a = 0; a < 10; ++a) {
    float r = wred(xs[a]);
    if (threadIdx.x == 0) atomicAdd(&sxs[100 + a], r);
#pragma unroll
    for (int b = 0; b < 10; ++b) {
      float r2 = wred(s[a][b]);
      if (threadIdx.x == 0) atomicAdd(&sxs[a * 10 + b], r2);
    }
  }
}

// ---- BN1 scale/shift from Sx quadratic form ----
__global__ void bn1_from_sx(const float* __restrict__ sxs, const float* __restrict__ Wc,
                            const float* __restrict__ bc, const float* __restrict__ g,
                            const float* __restrict__ b, float* __restrict__ s1,
                            float* __restrict__ c1) {
  int j = threadIdx.x;  // 128
  float w[10];
#pragma unroll
  for (int q = 0; q < 10; ++q) w[q] = Wc[q * 128 + j];
  float d = 0.f;
#pragma unroll
  for (int q = 0; q < 10; ++q) d += sxs[100 + q] * w[q];
  float qq = 0.f;
#pragma unroll
  for (int a = 0; a < 10; ++a) {
    float p = 0.f;
#pragma unroll
    for (int bq = 0; bq < 10; ++bq) p += sxs[a * 10 + bq] * w[bq];
    qq += w[a] * p;
  }
  float invE = 1.f / (float)NE;
  float bias = bc[j];
  float mean = d * invE + bias;
  float m2 = (qq + 2.f * bias * d) * invE + bias * bias;
  float var = fmaxf(m2 - mean * mean, 0.f);
  float sc = g[j] * rsqrtf(var + 1e-5f);
  s1[j] = sc;
  c1[j] = b[j] - mean * sc;
}

// ---- t[e,j] = leaky(bn1(xb@Wc + bc)) -> fp16 [NE,128]; 16 rows/block ----
__global__ __launch_bounds__(256) void t_kernel(const float* __restrict__ x,
                                                const float* __restrict__ es,
                                                const float* __restrict__ ec,
                                                const float* __restrict__ Wc,
                                                const float* __restrict__ bcb,
                                                const float* __restrict__ s1,
                                                const float* __restrict__ c1,
                                                __half* __restrict__ T, int E) {
  __shared__ float Wcl[1280], bcl[128], s1l[128], c1l[128], esl[10], ecl[10];
  __shared__ float xr[16][10];
  int t = threadIdx.x;
  for (int i = t; i < 1280; i += 256) Wcl[i] = Wc[i];
  if (t < 128) { bcl[t] = bcb[t]; s1l[t] = s1[t]; c1l[t] = c1[t]; }
  if (t < 10) { esl[t] = es[t]; ecl[t] = ec[t]; }
  int r0 = blockIdx.x * 16;
  if (t < 160) xr[t / 10][t % 10] = x[(size_t)r0 * 10 + t];
  __syncthreads();
  int rl = t >> 4, c0 = (t & 15) * 8;
  float acc[8];
#pragma unroll
  for (int j = 0; j < 8; ++j) acc[j] = bcl[c0 + j];
#pragma unroll
  for (int q = 0; q < 10; ++q) {
    float xb = xr[rl][q] * esl[q] + ecl[q];
#pragma unroll
    for (int j = 0; j < 8; ++j) acc[j] += xb * Wcl[q * 128 + c0 + j];
  }
  f16x8 o;
#pragma unroll
  for (int j = 0; j < 8; ++j) {
    float tv = acc[j] * s1l[c0 + j] + c1l[c0 + j];
    tv = tv > 0.f ? tv : 0.8f * tv;
    o[j] = (_Float16)tv;
  }
  *(f16x8*)&T[(size_t)(r0 + rl) * 128 + c0] = o;
}

// ---- tsum[128] = column sum of T (full path) ----
__global__ __launch_bounds__(256) void colsum_t(const __half* __restrict__ T,
                                                float* __restrict__ tsum, int E) {
  __shared__ float cs[128];
  int t = threadIdx.x;
  int col = t & 127, hf = t >> 7;
  float a = 0.f;
  for (int r = blockIdx.x * 2 + hf; r < E; r += gridDim.x * 2)
    a += __half2float(T[(size_t)r * 128 + col]);
  if (hf) cs[col] = a;
  __syncthreads();
  if (!hf) atomicAdd(&tsum[col], a + cs[col]);
}

// ---- MFMA S = T^T @ T: per-block 128x128 fp32 partial; one fragment set
//      serves as both A and B (B = A^T of T under identical lane maps). ----
__global__ __launch_bounds__(256) void tsq_mfma(const __half* __restrict__ T,
                                                float* __restrict__ partial, int E) {
  __shared__ _Float16 tl[32 * 132];  // pitch 132 halves: 2-way-free banks
  int t = threadIdx.x;
  int w = t >> 6, lane = t & 63;
  int g = lane >> 4, cl = lane & 15;
  f32x4 acc[2][8];
#pragma unroll
  for (int i = 0; i < 2; ++i)
#pragma unroll
    for (int j = 0; j < 8; ++j) acc[i][j] = {0.f, 0.f, 0.f, 0.f};
  int nch = E >> 5;  // 3125 (E % 32 == 0)
  for (int ch = blockIdx.x; ch < nch; ch += gridDim.x) {
    __syncthreads();
#pragma unroll
    for (int p = 0; p < 4; ++p) {  // stage 32x128 halves via uint2
      int u = p * 256 + t;
      int e = u >> 5, c0 = (u & 31) * 4;
      *(uint2*)&tl[e * 132 + c0] = *(const uint2*)&T[((size_t)ch * 32 + e) * 128 + c0];
    }
    __syncthreads();
    f16x8 fr[8];
#pragma unroll
    for (int cb = 0; cb < 8; ++cb) {
      f16x8 f;
#pragma unroll
      for (int j = 0; j < 8; ++j) f[j] = tl[(g * 8 + j) * 132 + cb * 16 + cl];
      fr[cb] = f;
    }
    f16x8 afr[2];  // wave's A-frags: runtime LDS addr (ok), static reg index
#pragma unroll
    for (int ri = 0; ri < 2; ++ri) {
      int cb = w * 2 + ri;
      f16x8 f;
#pragma unroll
      for (int j = 0; j < 8; ++j) f[j] = tl[(g * 8 + j) * 132 + cb * 16 + cl];
      afr[ri] = f;
    }
#pragma unroll
    for (int ri = 0; ri < 2; ++ri)
#pragma unroll
      for (int ci = 0; ci < 8; ++ci)
        acc[ri][ci] = __builtin_amdgcn_mfma_f32_16x16x32_f16(afr[ri], fr[ci], acc[ri][ci], 0, 0, 0);
  }
  float* pb = partial + (size_t)blockIdx.x * 16384;
#pragma unroll
  for (int ri = 0; ri < 2; ++ri)
#pragma unroll
    for (int ci = 0; ci < 8; ++ci)
#pragma unroll
      for (int q = 0; q < 4; ++q)
        pb[(w * 32 + ri * 16 + g * 4 + q) * 128 + ci * 16 + cl] = acc[ri][ci][q];
}

__global__ void tsq_reduce(const float* __restrict__ partial, float* __restrict__ S) {
  int i = blockIdx.x * 256 + threadIdx.x;  // 16384
  float a = 0.f;
  for (int b = 0; b < TSQ_NB; ++b) a += partial[(size_t)b * 16384 + i];
  S[i] = a;
}

// ---- compact-path fallback: VALU S + tsum with atomics ----
__global__ __launch_bounds__(256) void tsq_kernel(const __half* __restrict__ T,
                                                  float* __restrict__ S,
                                                  float* __restrict__ tsum, int E) {
  __shared__ float tt[16][128];
  int t = threadIdx.x;
  int ta = t >> 4, tb = t & 15;
  float acc[8][8];
#pragma unroll
  for (int a = 0; a < 8; ++a)
#pragma unroll
    for (int b = 0; b < 8; ++b) acc[a][b] = 0.f;
  float tsl = 0.f;
  int per = (E + gridDim.x - 1) / gridDim.x;
  int e0 = blockIdx.x * per;
  int e1 = min(E, e0 + per);
  for (int ec = e0; ec < e1; ec += 16) {
    __syncthreads();
    int rr = t >> 4, g8 = (t & 15) * 8;
    int e = ec + rr;
    uint4 u = make_uint4(0, 0, 0, 0);
    if (e < e1) u = *(const uint4*)&T[(size_t)e * 128 + g8];
    const __half* hp = (const __half*)&u;
#pragma unroll
    for (int q = 0; q < 8; ++q) tt[rr][g8 + q] = __half2float(hp[q]);
    __syncthreads();
    if (t < 128) {
#pragma unroll
      for (int r2 = 0; r2 < 16; ++r2) tsl += tt[r2][t];
    }
#pragma unroll
    for (int ee = 0; ee < 16; ++ee) {
      float va[8], vb[8];
#pragma unroll
      for (int q = 0; q < 8; ++q) { va[q] = tt[ee][ta * 8 + q]; vb[q] = tt[ee][tb * 8 + q]; }
#pragma unroll
      for (int a = 0; a < 8; ++a)
#pragma unroll
        for (int b = 0; b < 8; ++b) acc[a][b] += va[a] * vb[b];
    }
  }
#pragma unroll
  for (int a = 0; a < 8; ++a)
#pragma unroll
    for (int b = 0; b < 8; ++b) atomicAdd(&S[(ta * 8 + a) * 128 + tb * 8 + b], acc[a][b]);
  if (t < 128) atomicAdd(&tsum[t], tsl);
}

// ---- parallel BN2 from S quadratic form ----
__global__ __launch_bounds__(256) void bn2p(const float* __restrict__ S,
                                            const float* __restrict__ tsum,
                                            const float* __restrict__ W2,
                                            const float* __restrict__ b2,
                                            const float* __restrict__ g,
                                            const float* __restrict__ b,
                                            float* __restrict__ s2, float* __restrict__ c2p) {
  __shared__ float Sl[16384];
  __shared__ float tsl[128];
  for (int i = threadIdx.x; i < 16384; i += 256) Sl[i] = S[i];
  if (threadIdx.x < 128) tsl[threadIdx.x] = tsum[threadIdx.x];
  __syncthreads();
  int w = threadIdx.x >> 6, lane = threadIdx.x & 63;
  int io = blockIdx.x * 4 + w;
  float wlo = W2[(size_t)lane * 1024 + io];
  float whi = W2[(size_t)(lane + 64) * 1024 + io];
  float plo = 0.f, phi = 0.f;
#pragma unroll
  for (int a = 0; a < 64; ++a) {
    float wa = __shfl(wlo, a);
    plo += wa * Sl[a * 128 + lane];
    phi += wa * Sl[a * 128 + lane + 64];
  }
#pragma unroll
  for (int a = 0; a < 64; ++a) {
    float wa = __shfl(whi, a);
    plo += wa * Sl[(a + 64) * 128 + lane];
    phi += wa * Sl[(a + 64) * 128 + lane + 64];
  }
  float qq = wred(plo * wlo + phi * whi);
  float d = wred(wlo * tsl[lane] + whi * tsl[lane + 64]);
  if (lane == 0) {
    float invE = 1.f / (float)NE;
    float mean_raw = d * invE;
    float var = fmaxf(qq * invE - mean_raw * mean_raw, 0.f);
    float sc = g[io] * rsqrtf(var + 1e-5f);
    s2[io] = sc;
    c2p[io] = b[io] - (mean_raw + b2[io]) * sc;
  }
}

// ---- repack W2 into MFMA B-fragment layout, fp16 ----
__global__ void repack_w2(const float* __restrict__ W2, unsigned short* __restrict__ Bp) {
  int idx = blockIdx.x * 256 + threadIdx.x;
  if (idx >= 16384) return;
  int cb = idx >> 8;
  int ks = (idx >> 6) & 3;
  int lane = idx & 63;
  int col = cb * 16 + (lane & 15);
  int kbase = ks * 32 + (lane >> 4) * 8;
  unsigned short tmp[8];
#pragma unroll
  for (int j = 0; j < 8; ++j)
    tmp[j] = __half_as_ushort(__float2half(W2[(size_t)(kbase + j) * 1024 + col]));
  *(uint4*)&Bp[(size_t)idx * 8] = *(uint4*)tmp;
}

// ---- MFMA GEMM: We[e,io] = (T@W2)*s2 + c2p -> fp16 ----
__global__ __launch_bounds__(256) void gemm2_mfma(const __half* __restrict__ T,
                                                  const unsigned short* __restrict__ Bp,
                                                  const float* __restrict__ s2,
                                                  const float* __restrict__ c2p,
                                                  __half* __restrict__ We, int R) {
  int w = threadIdx.x >> 6, lane = threadIdx.x & 63;
  int r0 = blockIdx.y * 64;
  int cb0 = blockIdx.x * 16 + w * 4;
  f32x4 acc[4][4];
#pragma unroll
  for (int i = 0; i < 4; ++i)
#pragma unroll
    for (int j = 0; j < 4; ++j) acc[i][j] = {0.f, 0.f, 0.f, 0.f};
  int arow = lane & 15, kgrp = lane >> 4;
#pragma unroll
  for (int ks = 0; ks < 4; ++ks) {
    f16x8 a[4];
#pragma unroll
    for (int ri = 0; ri < 4; ++ri) {
      int r = r0 + ri * 16 + arow;
      f16x8 av{};
      if (r < R) av = *(const f16x8*)&T[(size_t)r * 128 + ks * 32 + kgrp * 8];
      a[ri] = av;
    }
#pragma unroll
    for (int ci = 0; ci < 4; ++ci) {
      f16x8 bv = *(const f16x8*)&Bp[((size_t)((cb0 + ci) * 4 + ks) * 64 + lane) * 8];
#pragma unroll
      for (int ri = 0; ri < 4; ++ri)
        acc[ri][ci] = __builtin_amdgcn_mfma_f32_16x16x32_f16(a[ri], bv, acc[ri][ci], 0, 0, 0);
    }
  }
#pragma unroll
  for (int ci = 0; ci < 4; ++ci) {
    int col = (cb0 + ci) * 16 + arow;
    float sc = s2[col];
    float cc = c2p[col];
#pragma unroll
    for (int ri = 0; ri < 4; ++ri) {
#pragma unroll
      for (int q = 0; q < 4; ++q) {
        int r = r0 + ri * 16 + kgrp * 4 + q;
        if (r < R)
          We[(size_t)r * 1024 + col] = __float2half(acc[ri][ci][q] * sc + cc);
      }
    }
  }
}

// ---- msg[e,o] = sum_i h[src,i]*We[e,i*32+o], scatter to m[dst] ----
__global__ __launch_bounds__(256) void msg_kernel(const __half* __restrict__ We,
                                                  const float* __restrict__ h,
                                                  const int* __restrict__ src,
                                                  const int* __restrict__ dst,
                                                  float* __restrict__ m, int E) {
  int gid = blockIdx.x * 256 + threadIdx.x;
  int e = gid >> 2;
  if (e >= E) return;
  int sub = gid & 3;
  int sn = src[e], dn = dst[e];
  float hv[32];
#pragma unroll
  for (int q = 0; q < 8; ++q) {
    float4 v = *(const float4*)&h[(size_t)sn * 32 + q * 4];
    hv[q * 4] = v.x; hv[q * 4 + 1] = v.y; hv[q * 4 + 2] = v.z; hv[q * 4 + 3] = v.w;
  }
  float acc[8];
#pragma unroll
  for (int j = 0; j < 8; ++j) acc[j] = 0.f;
  const __half* wp = We + (size_t)e * 1024 + sub * 8;
#pragma unroll
  for (int i = 0; i < 32; ++i) {
    uint4 u = *(const uint4*)(wp + i * 32);
    const __half* hp = (const __half*)&u;
    float hi = hv[i];
    acc[0] += hi * __half2float(hp[0]);
    acc[1] += hi * __half2float(hp[1]);
    acc[2] += hi * __half2float(hp[2]);
    acc[3] += hi * __half2float(hp[3]);
    acc[4] += hi * __half2float(hp[4]);
    acc[5] += hi * __half2float(hp[5]);
    acc[6] += hi * __half2float(hp[6]);
    acc[7] += hi * __half2float(hp[7]);
  }
  float* mp = m + (size_t)dn * 32 + sub * 8;
#pragma unroll
  for (int j = 0; j < 8; ++j) atomicAdd(&mp[j], acc[j]);
}

// ---- compact fallback: recompute We on the fly ----
__global__ __launch_bounds__(256) void msg_fused(const __half* __restrict__ T,
                                                 const float* __restrict__ W2,
                                                 const float* __restrict__ s2,
                                                 const float* __restrict__ c2p,
                                                 const float* __restrict__ h,
                                                 const int* __restrict__ src,
                                                 const int* __restrict__ dst,
                                                 float* __restrict__ m, int E) {
  __shared__ float tt[16][128];
  __shared__ float hs[16][32];
  __shared__ float w2s[8][1024];
  __shared__ float s2l[1024], c2l[1024];
  int t = threadIdx.x;
  for (int i = t; i < 1024; i += 256) { s2l[i] = s2[i]; c2l[i] = c2p[i]; }
  int e0 = blockIdx.x * 16;
  int le = t >> 5, o = t & 31;
  int eA = e0 + le, eB = e0 + 8 + le;
  bool vA = eA < E, vB = eB < E;
  int snA = vA ? src[eA] : 0, dnA = vA ? dst[eA] : 0;
  int snB = vB ? src[eB] : 0, dnB = vB ? dst[eB] : 0;
  {
    int rr = t >> 4, g8 = (t & 15) * 8;
    int ge = e0 + rr;
    uint4 u = make_uint4(0, 0, 0, 0);
    if (ge < E) u = *(const uint4*)&T[(size_t)ge * 128 + g8];
    const __half* hp = (const __half*)&u;
#pragma unroll
    for (int q = 0; q < 8; ++q) tt[rr][g8 + q] = __half2float(hp[q]);
  }
  hs[le][o] = vA ? h[(size_t)snA * 32 + o] : 0.f;
  hs[8 + le][o] = vB ? h[(size_t)snB * 32 + o] : 0.f;
  float rawA[32], rawB[32];
#pragma unroll
  for (int i = 0; i < 32; ++i) { rawA[i] = 0.f; rawB[i] = 0.f; }
  for (int kc = 0; kc < 16; ++kc) {
    __syncthreads();
#pragma unroll
    for (int j = 0; j < 8; ++j) {
      int idx = j * 256 + t;
      int rr = idx >> 8, cc = (idx & 255) * 4;
      *(float4*)&w2s[rr][cc] = *(const float4*)&W2[(size_t)(kc * 8 + rr) * 1024 + cc];
    }
    __syncthreads();
#pragma unroll
    for (int kk = 0; kk < 8; ++kk) {
      float tvA = tt[le][kc * 8 + kk], tvB = tt[8 + le][kc * 8 + kk];
#pragma unroll
      for (int i = 0; i < 32; ++i) {
        float w = w2s[kk][i * 32 + o];
        rawA[i] += tvA * w;
        rawB[i] += tvB * w;
      }
    }
  }
  float accA = 0.f, accB = 0.f;
#pragma unroll
  for (int i = 0; i < 32; ++i) {
    int io = i * 32 + o;
    accA += hs[le][i] * (rawA[i] * s2l[io] + c2l[io]);
    accB += hs[8 + le][i] * (rawB[i] * s2l[io] + c2l[io]);
  }
  if (vA) atomicAdd(&m[(size_t)dnA * 32 + o], accA);
  if (vB) atomicAdd(&m[(size_t)dnB * 32 + o], accB);
}

// ---- node embedding ----
template <int K, int COUT>
__global__ __launch_bounds__(256) void embed_gemm(const float* __restrict__ x,
                                                  const float* __restrict__ s,
                                                  const float* __restrict__ c,
                                                  const float* __restrict__ W,
                                                  const float* __restrict__ bias,
                                                  float* __restrict__ out, int R) {
  __shared__ float Wl[K * COUT];
  __shared__ float sl[K], cl[K];
  for (int i = threadIdx.x; i < K * COUT; i += 256) Wl[i] = W[i];
  for (int i = threadIdx.x; i < K; i += 256) { sl[i] = s[i]; cl[i] = c[i]; }
  __syncthreads();
  int gid = blockIdx.x * 256 + threadIdx.x;
  if (gid >= R * COUT) return;
  int r = gid / COUT, j = gid % COUT;
  float acc = bias[j];
#pragma unroll
  for (int k = 0; k < K; ++k) acc += (x[(size_t)r * K + k] * sl[k] + cl[k]) * Wl[k * COUT + j];
  out[gid] = acc;
}

// ---- GRU cell ----
__global__ __launch_bounds__(256) void gru_kernel(const float* __restrict__ m,
                                                  const float* __restrict__ inv_den,
                                                  const float* __restrict__ h_in,
                                                  const float* __restrict__ Wih,
                                                  const float* __restrict__ Whh,
                                                  const float* __restrict__ bih,
                                                  const float* __restrict__ bhh,
                                                  float* __restrict__ h_out, int N) {
  __shared__ float WT[32 * 96], UT[32 * 96];
  for (int idx = threadIdx.x; idx < 96 * 32; idx += 256) {
    int j = idx / 32, i = idx % 32;
    WT[i * 96 + j] = Wih[idx];
    UT[i * 96 + j] = Whh[idx];
  }
  __syncthreads();
  int gid = blockIdx.x * 256 + threadIdx.x;
  if (gid >= N * 32) return;
  int n = gid >> 5, o = gid & 31;
  float inv = inv_den[n];
  float air = 0.f, aiz = 0.f, ain = 0.f, ahr = 0.f, ahz = 0.f, ahn = 0.f;
#pragma unroll
  for (int i = 0; i < 32; ++i) {
    float mi = m[(size_t)n * 32 + i] * inv;
    float hi = h_in[(size_t)n * 32 + i];
    const float* w = &WT[i * 96 + o];
    const float* u = &UT[i * 96 + o];
    air += mi * w[0];  aiz += mi * w[32];  ain += mi * w[64];
    ahr += hi * u[0];  ahz += hi * u[32];  ahn += hi * u[64];
  }
  float r = 1.f / (1.f + expf(-(air + bih[o] + ahr + bhh[o])));
  float z = 1.f / (1.f + expf(-(aiz + bih[o + 32] + ahz + bhh[o + 32])));
  float ng = tanhf(ain + bih[o + 64] + r * (ahn + bhh[o + 64]));
  h_out[gid] = (1.f - z) * ng + z * h_in[(size_t)n * 32 + o];
}

extern "C" void kernel_launch(void* const* d_in, const int* in_sizes, int n_in,
                              void* d_out, int out_size, void* d_ws, size_t ws_size,
                              hipStream_t stream) {
  const float* x_node = (const float*)d_in[0];
  const float* x_edge = (const float*)d_in[1];
  const int* src = (const int*)d_in[2];
  const int* dst = (const int*)d_in[3];
  const float* bn_n_g = (const float*)d_in[4];
  const float* bn_n_b = (const float*)d_in[5];
  const float* node_W = (const float*)d_in[6];
  const float* node_b = (const float*)d_in[7];
  const float* bn_e_g = (const float*)d_in[8];
  const float* bn_e_b = (const float*)d_in[9];
  const float* edge_W = (const float*)d_in[10];
  const float* edge_b = (const float*)d_in[11];
  const float* en_W1 = (const float*)d_in[12];
  const float* en_b1 = (const float*)d_in[13];
  const float* en_bn1_g = (const float*)d_in[14];
  const float* en_bn1_b = (const float*)d_in[15];
  const float* en_W2 = (const float*)d_in[16];
  const float* en_b2 = (const float*)d_in[17];
  const float* en_bn2_g = (const float*)d_in[18];
  const float* en_bn2_b = (const float*)d_in[19];
  const float* gWih = (const float*)d_in[20];
  const float* gWhh = (const float*)d_in[21];
  const float* gbih = (const float*)d_in[22];
  const float* gbhh = (const float*)d_in[23];
  float* out = (float*)d_out;

  const size_t SZ_WE = 204800000;                 // NE*1024*2 (fp16); also tsq partials
  const size_t CORE = 33785600;
  const size_t FULL_NEED = SZ_WE + CORE;          // 238,585,600
  bool full = (ws_size >= FULL_NEED);

  char* ws = (char*)d_ws;
  size_t base = full ? SZ_WE : 0;
  __half* We   = (__half*)(ws + 0);               // full path only
  float* tsq_part = (float*)(ws + 0);             // reused before We is written
  __half* Tt   = (__half*)(ws + base);            // 25,600,000
  float* h_a   = (float*)(ws + base + 25600000);  //  2,560,000
  float* h_b   = (float*)(ws + base + 28160000);  //  2,560,000
  float* m_buf = (float*)(ws + base + 30720000);  //  2,560,000
  float* inv_den = (float*)(ws + base + 33280000);//     80,000
  // zeroed region: 36,896 floats
  float* zbase = (float*)(ws + base + 33360000);
  float* deg   = zbase;                           // 20000 f
  float* S     = zbase + 20000;                   // 16384 f
  float* tsum  = zbase + 36384;                   // 128 f
  float* sxs   = zbase + 36512;
  float* nstat = zbase + 36640;
  float* estat = zbase + 36768;
  // params (fully overwritten each launch)
  float* par = (float*)(ws + base + 33507584);
  float* ns = par + 0;    float* nc = par + 64;
  float* es = par + 128;  float* ec = par + 192;
  float* s1 = par + 256;  float* c1 = par + 384;
  float* wc = par + 512;                          // 1280 f
  float* bcb = par + 1792;                        // 128 f
  float* s2 = par + 1920; float* c2p = par + 2944;// 1024 f each
  unsigned short* Bp = (unsigned short*)(ws + base + 33523456);  // 262,144 B

  zerok<<<(36896 + 255) / 256, 256, 0, stream>>>(zbase, 36896);

  colstats<40><<<200, 256, 0, stream>>>(x_node, nstat, NN * 40);
  colstats<10><<<256, 256, 0, stream>>>(x_edge, estat, NE * 10);
  deg_kernel<<<(NE + 255) / 256, 256, 0, stream>>>(dst, deg, NE);
  finalize_bn<<<1, 64, 0, stream>>>(nstat, bn_n_g, bn_n_b, ns, nc, 40, 1.f / NN);
  finalize_bn<<<1, 64, 0, stream>>>(estat, bn_e_g, bn_e_b, es, ec, 10, 1.f / NE);
  invden_kernel<<<(NN + 255) / 256, 256, 0, stream>>>(deg, inv_den, NN);

  fold_w1<<<1, 256, 0, stream>>>(edge_W, edge_b, en_W1, en_b1, wc, bcb);
  sx_kernel<<<128, 64, 0, stream>>>(x_edge, es, ec, sxs, NE);
  bn1_from_sx<<<1, 128, 0, stream>>>(sxs, wc, bcb, en_bn1_g, en_bn1_b, s1, c1);
  t_kernel<<<NE / 16, 256, 0, stream>>>(x_edge, es, ec, wc, bcb, s1, c1, Tt, NE);

  if (full) {
    colsum_t<<<512, 256, 0, stream>>>(Tt, tsum, NE);
    tsq_mfma<<<TSQ_NB, 256, 0, stream>>>(Tt, tsq_part, NE);
    tsq_reduce<<<64, 256, 0, stream>>>(tsq_part, S);
  } else {
    tsq_kernel<<<256, 256, 0, stream>>>(Tt, S, tsum, NE);
  }
  bn2p<<<256, 256, 0, stream>>>(S, tsum, en_W2, en_b2, en_bn2_g, en_bn2_b, s2, c2p);

  embed_gemm<40, 32><<<(NN * 32 + 255) / 256, 256, 0, stream>>>(x_node, ns, nc, node_W, node_b, h_a, NN);

  if (full) {
    repack_w2<<<64, 256, 0, stream>>>(en_W2, Bp);
    dim3 g(4, (NE + 63) / 64);
    gemm2_mfma<<<g, 256, 0, stream>>>(Tt, Bp, s2, c2p, We, NE);
  }

  const float* hin = h_a;
  for (int l = 0; l < 3; ++l) {
    float* hout = (l == 0) ? h_b : (l == 1) ? h_a : out;
    zerok<<<(NN * 32 + 255) / 256, 256, 0, stream>>>(m_buf, NN * 32);
    if (full) {
      msg_kernel<<<(NE * 4 + 255) / 256, 256, 0, stream>>>(We, hin, src, dst, m_buf, NE);
    } else {
      msg_fused<<<(NE + 15) / 16, 256, 0, stream>>>(Tt, en_W2, s2, c2p, hin, src, dst, m_buf, NE);
    }
    gru_kernel<<<(NN * 32 + 255) / 256, 256, 0, stream>>>(m_buf, inv_den, hin, gWih, gWhh,
                                                          gbih, gbhh, hout, NN);
    hin = hout;
  }
}

// Round 5
// 786.345 us; speedup vs baseline: 2.1564x; 1.0378x over previous
//
#include <hip/hip_runtime.h>
#include <hip/hip_fp16.h>

#define NN 20000
#define NE 100000
#define TSQ_NB 256

typedef _Float16 f16x8 __attribute__((ext_vector_type(8)));
typedef float f32x4 __attribute__((ext_vector_type(4)));

__device__ __forceinline__ float wred(float v) {
#pragma unroll
  for (int k = 1; k < 64; k <<= 1) v += __shfl_xor(v, k);
  return v;
}

__global__ void zerok(float* __restrict__ p, int n) {
  int i = blockIdx.x * 256 + threadIdx.x;
  if (i < n) p[i] = 0.f;
}

// ---- per-column sum / sumsq over [R, C] fp32 ----
template <int C>
__global__ void colstats(const float* __restrict__ x, float* __restrict__ stat, int total) {
  __shared__ float ls[2 * C];
  for (int i = threadIdx.x; i < 2 * C; i += blockDim.x) ls[i] = 0.f;
  __syncthreads();
  for (int idx = blockIdx.x * blockDim.x + threadIdx.x; idx < total; idx += gridDim.x * blockDim.x) {
    float v = x[idx];
    int c = idx % C;
    atomicAdd(&ls[c], v);
    atomicAdd(&ls[C + c], v * v);
  }
  __syncthreads();
  for (int i = threadIdx.x; i < 2 * C; i += blockDim.x) atomicAdd(&stat[i], ls[i]);
}

__global__ void finalize_bn(const float* __restrict__ stat, const float* __restrict__ g,
                            const float* __restrict__ b, float* __restrict__ s_out,
                            float* __restrict__ c_out, int C, float invR) {
  int c = blockIdx.x * blockDim.x + threadIdx.x;
  if (c >= C) return;
  float mean = stat[c] * invR;
  float var = fmaxf(stat[C + c] * invR - mean * mean, 0.f);
  float sc = g[c] * rsqrtf(var + 1e-5f);
  s_out[c] = sc;
  c_out[c] = b[c] - mean * sc;
}

__global__ void deg_kernel(const int* __restrict__ dst, float* __restrict__ deg, int E) {
  int e = blockIdx.x * blockDim.x + threadIdx.x;
  if (e < E) atomicAdd(&deg[dst[e]], 1.f);
}

__global__ void invden_kernel(const float* __restrict__ deg, float* __restrict__ inv, int N) {
  int n = blockIdx.x * blockDim.x + threadIdx.x;
  if (n < N) inv[n] = 1.f / fmaxf(deg[n], 1.f);
}

// ---- Wc[10,128] = edge_W @ en_W1 ; bc[128] = edge_b @ en_W1 + en_b1 ----
__global__ void fold_w1(const float* __restrict__ edge_W, const float* __restrict__ edge_b,
                        const float* __restrict__ en_W1, const float* __restrict__ en_b1,
                        float* __restrict__ Wc, float* __restrict__ bc) {
  int t = threadIdx.x;
  for (int idx = t; idx < 1280; idx += 256) {
    int bq = idx >> 7, j = idx & 127;
    float a = 0.f;
    for (int q = 0; q < 128; ++q) a += edge_W[bq * 128 + q] * en_W1[q * 128 + j];
    Wc[idx] = a;
  }
  if (t < 128) {
    float a = en_b1[t];
    for (int q = 0; q < 128; ++q) a += edge_b[q] * en_W1[q * 128 + t];
    bc[t] = a;
  }
}

// ---- Sx[10][10] + xsum[10] over xb = x*es+ec ----
__global__ __launch_bounds__(64) void sx_kernel(const float* __restrict__ x,
                                                const float* __restrict__ es,
                                                const float* __restrict__ ec,
                                                float* __restrict__ sxs, int E) {
  float s[10][10], xs[10], esl[10], ecl[10];
#pragma unroll
  for (int a = 0; a < 10; ++a) {
    xs[a] = 0.f; esl[a] = es[a]; ecl[a] = ec[a];
#pragma unroll
    for (int b = 0; b < 10; ++b) s[a][b] = 0.f;
  }
  for (int e = blockIdx.x * 64 + threadIdx.x; e < E; e += gridDim.x * 64) {
    float xb[10];
#pragma unroll
    for (int q = 0; q < 10; ++q) xb[q] = x[(size_t)e * 10 + q] * esl[q] + ecl[q];
#pragma unroll
    for (int a = 0; a < 10; ++a) {
      xs[a] += xb[a];
#pragma unroll
      for (int b = 0; b < 10; ++b) s[a][b] += xb[a] * xb[b];
    }
  }
#pragma unroll
  for (int a = 0; a < 10; ++a) {
    float r = wred(xs[a]);
    if (threadIdx.x == 0) atomicAdd(&sxs[100 + a], r);
#pragma unroll
    for (int b = 0; b < 10; ++b) {
      float r2 = wred(s[a][b]);
      if (threadIdx.x == 0) atomicAdd(&sxs[a * 10 + b], r2);
    }
  }
}

// ---- BN1 scale/shift from Sx quadratic form ----
__global__ void bn1_from_sx(const float* __restrict__ sxs, const float* __restrict__ Wc,
                            const float* __restrict__ bc, const float* __restrict__ g,
                            const float* __restrict__ b, float* __restrict__ s1,
                            float* __restrict__ c1) {
  int j = threadIdx.x;  // 128
  float w[10];
#pragma unroll
  for (int q = 0; q < 10; ++q) w[q] = Wc[q * 128 + j];
  float d = 0.f;
#pragma unroll
  for (int q = 0; q < 10; ++q) d += sxs[100 + q] * w[q];
  float qq = 0.f;
#pragma unroll
  for (int a = 0; a < 10; ++a) {
    float p = 0.f;
#pragma unroll
    for (int bq = 0; bq < 10; ++bq) p += sxs[a * 10 + bq] * w[bq];
    qq += w[a] * p;
  }
  float invE = 1.f / (float)NE;
  float bias = bc[j];
  float mean = d * invE + bias;
  float m2 = (qq + 2.f * bias * d) * invE + bias * bias;
  float var = fmaxf(m2 - mean * mean, 0.f);
  float sc = g[j] * rsqrtf(var + 1e-5f);
  s1[j] = sc;
  c1[j] = b[j] - mean * sc;
}

// ---- t[e,j] = leaky(bn1(xb@Wc + bc)) -> fp16 [NE,128]; 16 rows/block ----
__global__ __launch_bounds__(256) void t_kernel(const float* __restrict__ x,
                                                const float* __restrict__ es,
                                                const float* __restrict__ ec,
                                                const float* __restrict__ Wc,
                                                const float* __restrict__ bcb,
                                                const float* __restrict__ s1,
                                                const float* __restrict__ c1,
                                                __half* __restrict__ T, int E) {
  __shared__ float Wcl[1280], bcl[128], s1l[128], c1l[128], esl[10], ecl[10];
  __shared__ float xr[16][10];
  int t = threadIdx.x;
  for (int i = t; i < 1280; i += 256) Wcl[i] = Wc[i];
  if (t < 128) { bcl[t] = bcb[t]; s1l[t] = s1[t]; c1l[t] = c1[t]; }
  if (t < 10) { esl[t] = es[t]; ecl[t] = ec[t]; }
  int r0 = blockIdx.x * 16;
  if (t < 160) xr[t / 10][t % 10] = x[(size_t)r0 * 10 + t];
  __syncthreads();
  int rl = t >> 4, c0 = (t & 15) * 8;
  float acc[8];
#pragma unroll
  for (int j = 0; j < 8; ++j) acc[j] = bcl[c0 + j];
#pragma unroll
  for (int q = 0; q < 10; ++q) {
    float xb = xr[rl][q] * esl[q] + ecl[q];
#pragma unroll
    for (int j = 0; j < 8; ++j) acc[j] += xb * Wcl[q * 128 + c0 + j];
  }
  f16x8 o;
#pragma unroll
  for (int j = 0; j < 8; ++j) {
    float tv = acc[j] * s1l[c0 + j] + c1l[c0 + j];
    tv = tv > 0.f ? tv : 0.8f * tv;
    o[j] = (_Float16)tv;
  }
  *(f16x8*)&T[(size_t)(r0 + rl) * 128 + c0] = o;
}

// ---- tsum[128] = column sum of T ----
__global__ __launch_bounds__(256) void colsum_t(const __half* __restrict__ T,
                                                float* __restrict__ tsum, int E) {
  __shared__ float cs[128];
  int t = threadIdx.x;
  int col = t & 127, hf = t >> 7;
  float a = 0.f;
  for (int r = blockIdx.x * 2 + hf; r < E; r += gridDim.x * 2)
    a += __half2float(T[(size_t)r * 128 + col]);
  if (hf) cs[col] = a;
  __syncthreads();
  if (!hf) atomicAdd(&tsum[col], a + cs[col]);
}

// ---- MFMA S = T^T @ T: per-block 128x128 fp32 partial ----
__global__ __launch_bounds__(256) void tsq_mfma(const __half* __restrict__ T,
                                                float* __restrict__ partial, int E) {
  __shared__ _Float16 tl[32 * 132];
  int t = threadIdx.x;
  int w = t >> 6, lane = t & 63;
  int g = lane >> 4, cl = lane & 15;
  f32x4 acc[2][8];
#pragma unroll
  for (int i = 0; i < 2; ++i)
#pragma unroll
    for (int j = 0; j < 8; ++j) acc[i][j] = {0.f, 0.f, 0.f, 0.f};
  int nch = E >> 5;
  for (int ch = blockIdx.x; ch < nch; ch += gridDim.x) {
    __syncthreads();
#pragma unroll
    for (int p = 0; p < 4; ++p) {
      int u = p * 256 + t;
      int e = u >> 5, c0 = (u & 31) * 4;
      *(uint2*)&tl[e * 132 + c0] = *(const uint2*)&T[((size_t)ch * 32 + e) * 128 + c0];
    }
    __syncthreads();
    f16x8 fr[8];
#pragma unroll
    for (int cb = 0; cb < 8; ++cb) {
      f16x8 f;
#pragma unroll
      for (int j = 0; j < 8; ++j) f[j] = tl[(g * 8 + j) * 132 + cb * 16 + cl];
      fr[cb] = f;
    }
    f16x8 afr[2];
#pragma unroll
    for (int ri = 0; ri < 2; ++ri) {
      int cb = w * 2 + ri;
      f16x8 f;
#pragma unroll
      for (int j = 0; j < 8; ++j) f[j] = tl[(g * 8 + j) * 132 + cb * 16 + cl];
      afr[ri] = f;
    }
#pragma unroll
    for (int ri = 0; ri < 2; ++ri)
#pragma unroll
      for (int ci = 0; ci < 8; ++ci)
        acc[ri][ci] = __builtin_amdgcn_mfma_f32_16x16x32_f16(afr[ri], fr[ci], acc[ri][ci], 0, 0, 0);
  }
  float* pb = partial + (size_t)blockIdx.x * 16384;
#pragma unroll
  for (int ri = 0; ri < 2; ++ri)
#pragma unroll
    for (int ci = 0; ci < 8; ++ci)
#pragma unroll
      for (int q = 0; q < 4; ++q)
        pb[(w * 32 + ri * 16 + g * 4 + q) * 128 + ci * 16 + cl] = acc[ri][ci][q];
}

__global__ void tsq_reduce(const float* __restrict__ partial, float* __restrict__ S) {
  int i = blockIdx.x * 256 + threadIdx.x;  // 16384
  float a = 0.f;
  for (int b = 0; b < TSQ_NB; ++b) a += partial[(size_t)b * 16384 + i];
  S[i] = a;
}

// ---- compact-path fallback ----
__global__ __launch_bounds__(256) void tsq_kernel(const __half* __restrict__ T,
                                                  float* __restrict__ S,
                                                  float* __restrict__ tsum, int E) {
  __shared__ float tt[16][128];
  int t = threadIdx.x;
  int ta = t >> 4, tb = t & 15;
  float acc[8][8];
#pragma unroll
  for (int a = 0; a < 8; ++a)
#pragma unroll
    for (int b = 0; b < 8; ++b) acc[a][b] = 0.f;
  float tsl = 0.f;
  int per = (E + gridDim.x - 1) / gridDim.x;
  int e0 = blockIdx.x * per;
  int e1 = min(E, e0 + per);
  for (int ec = e0; ec < e1; ec += 16) {
    __syncthreads();
    int rr = t >> 4, g8 = (t & 15) * 8;
    int e = ec + rr;
    uint4 u = make_uint4(0, 0, 0, 0);
    if (e < e1) u = *(const uint4*)&T[(size_t)e * 128 + g8];
    const __half* hp = (const __half*)&u;
#pragma unroll
    for (int q = 0; q < 8; ++q) tt[rr][g8 + q] = __half2float(hp[q]);
    __syncthreads();
    if (t < 128) {
#pragma unroll
      for (int r2 = 0; r2 < 16; ++r2) tsl += tt[r2][t];
    }
#pragma unroll
    for (int ee = 0; ee < 16; ++ee) {
      float va[8], vb[8];
#pragma unroll
      for (int q = 0; q < 8; ++q) { va[q] = tt[ee][ta * 8 + q]; vb[q] = tt[ee][tb * 8 + q]; }
#pragma unroll
      for (int a = 0; a < 8; ++a)
#pragma unroll
        for (int b = 0; b < 8; ++b) acc[a][b] += va[a] * vb[b];
    }
  }
#pragma unroll
  for (int a = 0; a < 8; ++a)
#pragma unroll
    for (int b = 0; b < 8; ++b) atomicAdd(&S[(ta * 8 + a) * 128 + tb * 8 + b], acc[a][b]);
  if (t < 128) atomicAdd(&tsum[t], tsl);
}

// ---- parallel BN2 from S quadratic form ----
__global__ __launch_bounds__(256) void bn2p(const float* __restrict__ S,
                                            const float* __restrict__ tsum,
                                            const float* __restrict__ W2,
                                            const float* __restrict__ b2,
                                            const float* __restrict__ g,
                                            const float* __restrict__ b,
                                            float* __restrict__ s2, float* __restrict__ c2p) {
  __shared__ float Sl[16384];
  __shared__ float tsl[128];
  for (int i = threadIdx.x; i < 16384; i += 256) Sl[i] = S[i];
  if (threadIdx.x < 128) tsl[threadIdx.x] = tsum[threadIdx.x];
  __syncthreads();
  int w = threadIdx.x >> 6, lane = threadIdx.x & 63;
  int io = blockIdx.x * 4 + w;
  float wlo = W2[(size_t)lane * 1024 + io];
  float whi = W2[(size_t)(lane + 64) * 1024 + io];
  float plo = 0.f, phi = 0.f;
#pragma unroll
  for (int a = 0; a < 64; ++a) {
    float wa = __shfl(wlo, a);
    plo += wa * Sl[a * 128 + lane];
    phi += wa * Sl[a * 128 + lane + 64];
  }
#pragma unroll
  for (int a = 0; a < 64; ++a) {
    float wa = __shfl(whi, a);
    plo += wa * Sl[(a + 64) * 128 + lane];
    phi += wa * Sl[(a + 64) * 128 + lane + 64];
  }
  float qq = wred(plo * wlo + phi * whi);
  float d = wred(wlo * tsl[lane] + whi * tsl[lane + 64]);
  if (lane == 0) {
    float invE = 1.f / (float)NE;
    float mean_raw = d * invE;
    float var = fmaxf(qq * invE - mean_raw * mean_raw, 0.f);
    float sc = g[io] * rsqrtf(var + 1e-5f);
    s2[io] = sc;
    c2p[io] = b[io] - (mean_raw + b2[io]) * sc;
  }
}

// ---- repack W2 into MFMA B-fragment layout, fp16 ----
__global__ void repack_w2(const float* __restrict__ W2, unsigned short* __restrict__ Bp) {
  int idx = blockIdx.x * 256 + threadIdx.x;
  if (idx >= 16384) return;
  int cb = idx >> 8;
  int ks = (idx >> 6) & 3;
  int lane = idx & 63;
  int col = cb * 16 + (lane & 15);
  int kbase = ks * 32 + (lane >> 4) * 8;
  unsigned short tmp[8];
#pragma unroll
  for (int j = 0; j < 8; ++j)
    tmp[j] = __half_as_ushort(__float2half(W2[(size_t)(kbase + j) * 1024 + col]));
  *(uint4*)&Bp[(size_t)idx * 8] = *(uint4*)tmp;
}

// ---- MFMA GEMM with LDS-coalesced epilogue: We = (T@W2)*s2 + c2p -> fp16 ----
__global__ __launch_bounds__(256) void gemm2_mfma(const __half* __restrict__ T,
                                                  const unsigned short* __restrict__ Bp,
                                                  const float* __restrict__ s2,
                                                  const float* __restrict__ c2p,
                                                  __half* __restrict__ We, int R) {
  __shared__ _Float16 ot[64][260];  // pad 4: fragment b16 stores 2-way-free
  int t = threadIdx.x;
  int w = t >> 6, lane = t & 63;
  int r0 = blockIdx.y * 64;
  int c0 = blockIdx.x * 256;
  int cb0 = blockIdx.x * 16 + w * 4;
  f32x4 acc[4][4];
#pragma unroll
  for (int i = 0; i < 4; ++i)
#pragma unroll
    for (int j = 0; j < 4; ++j) acc[i][j] = {0.f, 0.f, 0.f, 0.f};
  int arow = lane & 15, kgrp = lane >> 4;
#pragma unroll
  for (int ks = 0; ks < 4; ++ks) {
    f16x8 a[4];
#pragma unroll
    for (int ri = 0; ri < 4; ++ri) {
      int r = r0 + ri * 16 + arow;
      f16x8 av{};
      if (r < R) av = *(const f16x8*)&T[(size_t)r * 128 + ks * 32 + kgrp * 8];
      a[ri] = av;
    }
#pragma unroll
    for (int ci = 0; ci < 4; ++ci) {
      f16x8 bv = *(const f16x8*)&Bp[((size_t)((cb0 + ci) * 4 + ks) * 64 + lane) * 8];
#pragma unroll
      for (int ri = 0; ri < 4; ++ri)
        acc[ri][ci] = __builtin_amdgcn_mfma_f32_16x16x32_f16(a[ri], bv, acc[ri][ci], 0, 0, 0);
    }
  }
  // fragments -> LDS (2-way-free b16 stores)
#pragma unroll
  for (int ci = 0; ci < 4; ++ci) {
    int colL = w * 64 + ci * 16 + arow;
    float sc = s2[c0 + colL];
    float cc = c2p[c0 + colL];
#pragma unroll
    for (int ri = 0; ri < 4; ++ri)
#pragma unroll
      for (int q = 0; q < 4; ++q)
        ot[ri * 16 + kgrp * 4 + q][colL] = (_Float16)(acc[ri][ci][q] * sc + cc);
  }
  __syncthreads();
  // coalesced writeout: 16B/lane, contiguous 512B rows
#pragma unroll
  for (int j = 0; j < 8; ++j) {
    int lin = j * 256 + t;
    int row = lin >> 5;
    int colh = (lin & 31) * 8;
    int r = r0 + row;
    if (r < R)
      *(uint4*)&We[(size_t)r * 1024 + c0 + colh] = *(const uint4*)&ot[row][colh];
  }
}

// ---- h (fp32) -> h2 (fp16), 4 elems/thread ----
__global__ void h2cvt(const float* __restrict__ h, __half* __restrict__ o, int n4) {
  int i = blockIdx.x * 256 + threadIdx.x;
  if (i >= n4) return;
  float4 v = *(const float4*)&h[(size_t)i * 4];
  __half hs[4];
  hs[0] = __float2half(v.x); hs[1] = __float2half(v.y);
  hs[2] = __float2half(v.z); hs[3] = __float2half(v.w);
  *(uint2*)&o[(size_t)i * 4] = *(uint2*)hs;
}

// ---- msg v2: 4 lanes/edge, 4 groups of 8 k-rows, all-static reg indices ----
__global__ __launch_bounds__(256, 2) void msg_kernel(const __half* __restrict__ We,
                                                     const __half* __restrict__ h2,
                                                     const int* __restrict__ src,
                                                     const int* __restrict__ dst,
                                                     float* __restrict__ m, int E) {
  int gid = blockIdx.x * 256 + threadIdx.x;
  int e = gid >> 2;
  if (e >= E) return;
  int sub = gid & 3;
  int sn = src[e], dn = dst[e];
  const f16x8* hp = (const f16x8*)&h2[(size_t)sn * 32];
  const __half* wp = We + (size_t)e * 1024 + sub * 8;
  float acc[8] = {0.f, 0.f, 0.f, 0.f, 0.f, 0.f, 0.f, 0.f};
#pragma unroll 2
  for (int g = 0; g < 4; ++g) {
    f16x8 hg = hp[g];
    const __half* wgp = wp + g * 256;
    f16x8 w0 = *(const f16x8*)(wgp);
    f16x8 w1 = *(const f16x8*)(wgp + 32);
    f16x8 w2 = *(const f16x8*)(wgp + 64);
    f16x8 w3 = *(const f16x8*)(wgp + 96);
    f16x8 w4 = *(const f16x8*)(wgp + 128);
    f16x8 w5 = *(const f16x8*)(wgp + 160);
    f16x8 w6 = *(const f16x8*)(wgp + 192);
    f16x8 w7 = *(const f16x8*)(wgp + 224);
#define MACC(wv, idx)                                                     \
  {                                                                       \
    float hf = (float)hg[idx];                                            \
    acc[0] += hf * (float)wv[0]; acc[1] += hf * (float)wv[1];             \
    acc[2] += hf * (float)wv[2]; acc[3] += hf * (float)wv[3];             \
    acc[4] += hf * (float)wv[4]; acc[5] += hf * (float)wv[5];             \
    acc[6] += hf * (float)wv[6]; acc[7] += hf * (float)wv[7];             \
  }
    MACC(w0, 0) MACC(w1, 1) MACC(w2, 2) MACC(w3, 3)
    MACC(w4, 4) MACC(w5, 5) MACC(w6, 6) MACC(w7, 7)
#undef MACC
  }
  float* mp = m + (size_t)dn * 32 + sub * 8;
#pragma unroll
  for (int j = 0; j < 8; ++j) atomicAdd(&mp[j], acc[j]);
}

// ---- compact fallback: recompute We on the fly (fp32 h) ----
__global__ __launch_bounds__(256) void msg_fused(const __half* __restrict__ T,
                                                 const float* __restrict__ W2,
                                                 const float* __restrict__ s2,
                                                 const float* __restrict__ c2p,
                                                 const float* __restrict__ h,
                                                 const int* __restrict__ src,
                                                 const int* __restrict__ dst,
                                                 float* __restrict__ m, int E) {
  __shared__ float tt[16][128];
  __shared__ float hs[16][32];
  __shared__ float w2s[8][1024];
  __shared__ float s2l[1024], c2l[1024];
  int t = threadIdx.x;
  for (int i = t; i < 1024; i += 256) { s2l[i] = s2[i]; c2l[i] = c2p[i]; }
  int e0 = blockIdx.x * 16;
  int le = t >> 5, o = t & 31;
  int eA = e0 + le, eB = e0 + 8 + le;
  bool vA = eA < E, vB = eB < E;
  int snA = vA ? src[eA] : 0, dnA = vA ? dst[eA] : 0;
  int snB = vB ? src[eB] : 0, dnB = vB ? dst[eB] : 0;
  {
    int rr = t >> 4, g8 = (t & 15) * 8;
    int ge = e0 + rr;
    uint4 u = make_uint4(0, 0, 0, 0);
    if (ge < E) u = *(const uint4*)&T[(size_t)ge * 128 + g8];
    const __half* hp = (const __half*)&u;
#pragma unroll
    for (int q = 0; q < 8; ++q) tt[rr][g8 + q] = __half2float(hp[q]);
  }
  hs[le][o] = vA ? h[(size_t)snA * 32 + o] : 0.f;
  hs[8 + le][o] = vB ? h[(size_t)snB * 32 + o] : 0.f;
  float rawA[32], rawB[32];
#pragma unroll
  for (int i = 0; i < 32; ++i) { rawA[i] = 0.f; rawB[i] = 0.f; }
  for (int kc = 0; kc < 16; ++kc) {
    __syncthreads();
#pragma unroll
    for (int j = 0; j < 8; ++j) {
      int idx = j * 256 + t;
      int rr = idx >> 8, cc = (idx & 255) * 4;
      *(float4*)&w2s[rr][cc] = *(const float4*)&W2[(size_t)(kc * 8 + rr) * 1024 + cc];
    }
    __syncthreads();
#pragma unroll
    for (int kk = 0; kk < 8; ++kk) {
      float tvA = tt[le][kc * 8 + kk], tvB = tt[8 + le][kc * 8 + kk];
#pragma unroll
      for (int i = 0; i < 32; ++i) {
        float w = w2s[kk][i * 32 + o];
        rawA[i] += tvA * w;
        rawB[i] += tvB * w;
      }
    }
  }
  float accA = 0.f, accB = 0.f;
#pragma unroll
  for (int i = 0; i < 32; ++i) {
    int io = i * 32 + o;
    accA += hs[le][i] * (rawA[i] * s2l[io] + c2l[io]);
    accB += hs[8 + le][i] * (rawB[i] * s2l[io] + c2l[io]);
  }
  if (vA) atomicAdd(&m[(size_t)dnA * 32 + o], accA);
  if (vB) atomicAdd(&m[(size_t)dnB * 32 + o], accB);
}

// ---- node embedding ----
template <int K, int COUT>
__global__ __launch_bounds__(256) void embed_gemm(const float* __restrict__ x,
                                                  const float* __restrict__ s,
                                                  const float* __restrict__ c,
                                                  const float* __restrict__ W,
                                                  const float* __restrict__ bias,
                                                  float* __restrict__ out, int R) {
  __shared__ float Wl[K * COUT];
  __shared__ float sl[K], cl[K];
  for (int i = threadIdx.x; i < K * COUT; i += 256) Wl[i] = W[i];
  for (int i = threadIdx.x; i < K; i += 256) { sl[i] = s[i]; cl[i] = c[i]; }
  __syncthreads();
  int gid = blockIdx.x * 256 + threadIdx.x;
  if (gid >= R * COUT) return;
  int r = gid / COUT, j = gid % COUT;
  float acc = bias[j];
#pragma unroll
  for (int k = 0; k < K; ++k) acc += (x[(size_t)r * K + k] * sl[k] + cl[k]) * Wl[k * COUT + j];
  out[gid] = acc;
}

// ---- GRU cell ----
__global__ __launch_bounds__(256) void gru_kernel(const float* __restrict__ m,
                                                  const float* __restrict__ inv_den,
                                                  const float* __restrict__ h_in,
                                                  const float* __restrict__ Wih,
                                                  const float* __restrict__ Whh,
                                                  const float* __restrict__ bih,
                                                  const float* __restrict__ bhh,
                                                  float* __restrict__ h_out, int N) {
  __shared__ float WT[32 * 96], UT[32 * 96];
  for (int idx = threadIdx.x; idx < 96 * 32; idx += 256) {
    int j = idx / 32, i = idx % 32;
    WT[i * 96 + j] = Wih[idx];
    UT[i * 96 + j] = Whh[idx];
  }
  __syncthreads();
  int gid = blockIdx.x * 256 + threadIdx.x;
  if (gid >= N * 32) return;
  int n = gid >> 5, o = gid & 31;
  float inv = inv_den[n];
  float air = 0.f, aiz = 0.f, ain = 0.f, ahr = 0.f, ahz = 0.f, ahn = 0.f;
#pragma unroll
  for (int i = 0; i < 32; ++i) {
    float mi = m[(size_t)n * 32 + i] * inv;
    float hi = h_in[(size_t)n * 32 + i];
    const float* w = &WT[i * 96 + o];
    const float* u = &UT[i * 96 + o];
    air += mi * w[0];  aiz += mi * w[32];  ain += mi * w[64];
    ahr += hi * u[0];  ahz += hi * u[32];  ahn += hi * u[64];
  }
  float r = 1.f / (1.f + expf(-(air + bih[o] + ahr + bhh[o])));
  float z = 1.f / (1.f + expf(-(aiz + bih[o + 32] + ahz + bhh[o + 32])));
  float ng = tanhf(ain + bih[o + 64] + r * (ahn + bhh[o + 64]));
  h_out[gid] = (1.f - z) * ng + z * h_in[(size_t)n * 32 + o];
}

extern "C" void kernel_launch(void* const* d_in, const int* in_sizes, int n_in,
                              void* d_out, int out_size, void* d_ws, size_t ws_size,
                              hipStream_t stream) {
  const float* x_node = (const float*)d_in[0];
  const float* x_edge = (const float*)d_in[1];
  const int* src = (const int*)d_in[2];
  const int* dst = (const int*)d_in[3];
  const float* bn_n_g = (const float*)d_in[4];
  const float* bn_n_b = (const float*)d_in[5];
  const float* node_W = (const float*)d_in[6];
  const float* node_b = (const float*)d_in[7];
  const float* bn_e_g = (const float*)d_in[8];
  const float* bn_e_b = (const float*)d_in[9];
  const float* edge_W = (const float*)d_in[10];
  const float* edge_b = (const float*)d_in[11];
  const float* en_W1 = (const float*)d_in[12];
  const float* en_b1 = (const float*)d_in[13];
  const float* en_bn1_g = (const float*)d_in[14];
  const float* en_bn1_b = (const float*)d_in[15];
  const float* en_W2 = (const float*)d_in[16];
  const float* en_b2 = (const float*)d_in[17];
  const float* en_bn2_g = (const float*)d_in[18];
  const float* en_bn2_b = (const float*)d_in[19];
  const float* gWih = (const float*)d_in[20];
  const float* gWhh = (const float*)d_in[21];
  const float* gbih = (const float*)d_in[22];
  const float* gbhh = (const float*)d_in[23];
  float* out = (float*)d_out;

  const size_t SZ_WE = 204800000;                 // NE*1024*2 (fp16); also tsq partials
  const size_t CORE = 33785600;
  const size_t FULL_NEED = SZ_WE + CORE;          // 238,585,600
  bool full = (ws_size >= FULL_NEED);

  char* ws = (char*)d_ws;
  size_t base = full ? SZ_WE : 0;
  __half* We   = (__half*)(ws + 0);               // full path only
  float* tsq_part = (float*)(ws + 0);             // reused before We is written
  __half* Tt   = (__half*)(ws + base);            // 25,600,000 (dead after gemm2)
  __half* h2   = (__half*)(ws + base);            // reuses Tt space (full path, post-gemm2)
  float* h_a   = (float*)(ws + base + 25600000);
  float* h_b   = (float*)(ws + base + 28160000);
  float* m_buf = (float*)(ws + base + 30720000);
  float* inv_den = (float*)(ws + base + 33280000);
  float* zbase = (float*)(ws + base + 33360000);
  float* deg   = zbase;                           // 20000 f
  float* S     = zbase + 20000;                   // 16384 f
  float* tsum  = zbase + 36384;                   // 128 f
  float* sxs   = zbase + 36512;
  float* nstat = zbase + 36640;
  float* estat = zbase + 36768;
  float* par = (float*)(ws + base + 33507584);
  float* ns = par + 0;    float* nc = par + 64;
  float* es = par + 128;  float* ec = par + 192;
  float* s1 = par + 256;  float* c1 = par + 384;
  float* wc = par + 512;
  float* bcb = par + 1792;
  float* s2 = par + 1920; float* c2p = par + 2944;
  unsigned short* Bp = (unsigned short*)(ws + base + 33523456);

  zerok<<<(36896 + 255) / 256, 256, 0, stream>>>(zbase, 36896);

  colstats<40><<<200, 256, 0, stream>>>(x_node, nstat, NN * 40);
  colstats<10><<<256, 256, 0, stream>>>(x_edge, estat, NE * 10);
  deg_kernel<<<(NE + 255) / 256, 256, 0, stream>>>(dst, deg, NE);
  finalize_bn<<<1, 64, 0, stream>>>(nstat, bn_n_g, bn_n_b, ns, nc, 40, 1.f / NN);
  finalize_bn<<<1, 64, 0, stream>>>(estat, bn_e_g, bn_e_b, es, ec, 10, 1.f / NE);
  invden_kernel<<<(NN + 255) / 256, 256, 0, stream>>>(deg, inv_den, NN);

  fold_w1<<<1, 256, 0, stream>>>(edge_W, edge_b, en_W1, en_b1, wc, bcb);
  sx_kernel<<<128, 64, 0, stream>>>(x_edge, es, ec, sxs, NE);
  bn1_from_sx<<<1, 128, 0, stream>>>(sxs, wc, bcb, en_bn1_g, en_bn1_b, s1, c1);
  t_kernel<<<NE / 16, 256, 0, stream>>>(x_edge, es, ec, wc, bcb, s1, c1, Tt, NE);

  if (full) {
    colsum_t<<<512, 256, 0, stream>>>(Tt, tsum, NE);
    tsq_mfma<<<TSQ_NB, 256, 0, stream>>>(Tt, tsq_part, NE);
    tsq_reduce<<<64, 256, 0, stream>>>(tsq_part, S);
  } else {
    tsq_kernel<<<256, 256, 0, stream>>>(Tt, S, tsum, NE);
  }
  bn2p<<<256, 256, 0, stream>>>(S, tsum, en_W2, en_b2, en_bn2_g, en_bn2_b, s2, c2p);

  embed_gemm<40, 32><<<(NN * 32 + 255) / 256, 256, 0, stream>>>(x_node, ns, nc, node_W, node_b, h_a, NN);

  if (full) {
    repack_w2<<<64, 256, 0, stream>>>(en_W2, Bp);
    dim3 g(4, (NE + 63) / 64);
    gemm2_mfma<<<g, 256, 0, stream>>>(Tt, Bp, s2, c2p, We, NE);
  }

  const float* hin = h_a;
  for (int l = 0; l < 3; ++l) {
    float* hout = (l == 0) ? h_b : (l == 1) ? h_a : out;
    zerok<<<(NN * 32 + 255) / 256, 256, 0, stream>>>(m_buf, NN * 32);
    if (full) {
      h2cvt<<<(NN * 32 / 4 + 255) / 256, 256, 0, stream>>>(hin, h2, NN * 32 / 4);
      msg_kernel<<<(NE * 4 + 255) / 256, 256, 0, stream>>>(We, h2, src, dst, m_buf, NE);
    } else {
      msg_fused<<<(NE + 15) / 16, 256, 0, stream>>>(Tt, en_W2, s2, c2p, hin, src, dst, m_buf, NE);
    }
    gru_kernel<<<(NN * 32 + 255) / 256, 256, 0, stream>>>(m_buf, inv_den, hin, gWih, gWhh,
                                                          gbih, gbhh, hout, NN);
    hin = hout;
  }
}